// Round 11
// baseline (572.292 us; speedup 1.0000x reference)
//
#include <hip/hip_runtime.h>
#include <hip/hip_bf16.h>
#include <cstdint>

#define DMODEL 768
#define NB 64
#define NHEAD 12
#define DHEAD 64
#define SEQLEN 512
#define NDOM 3
#define NBLK 2
#define FFNH 3072
#define NBROWS (NDOM*NB)   // 192
#define NCH 8              // 64-row chunks
#define ROWCH 64

typedef __attribute__((ext_vector_type(8))) short short8;
typedef __attribute__((ext_vector_type(4))) float f32x4;

__device__ __forceinline__ float wsum64(float v){
  #pragma unroll
  for (int o = 32; o; o >>= 1) v += __shfl_xor(v, o, 64);
  return v;
}
__device__ __forceinline__ float dot4f(float4 a, float4 b){
  return fmaf(a.x, b.x, fmaf(a.y, b.y, fmaf(a.z, b.z, a.w * b.w)));
}
__device__ __forceinline__ uint32_t bfpair(float lo, float hi){
  uint32_t ul = __float_as_uint(lo), uh = __float_as_uint(hi);
  ul = (ul + 0x7FFFu + ((ul >> 16) & 1u)) >> 16;
  uh = (uh + 0x7FFFu + ((uh >> 16) & 1u)) & 0xFFFF0000u;
  return ul | uh;
}

// -------- LayerNorm: one wave per row --------
__global__ __launch_bounds__(256) void k_ln(const float* __restrict__ in,
    const float* __restrict__ w, const float* __restrict__ b,
    float* __restrict__ out, int rows){
  int gw = (blockIdx.x * 256 + threadIdx.x) >> 6;
  int lane = threadIdx.x & 63;
  if (gw >= rows) return;
  const float4* x4 = (const float4*)(in + (size_t)gw * DMODEL);
  float4 v0 = x4[lane], v1 = x4[64 + lane], v2 = x4[128 + lane];
  float s = v0.x+v0.y+v0.z+v0.w + v1.x+v1.y+v1.z+v1.w + v2.x+v2.y+v2.z+v2.w;
  float q = dot4f(v0,v0) + dot4f(v1,v1) + dot4f(v2,v2);
  s = wsum64(s); q = wsum64(q);
  float m = s * (1.0f / DMODEL);
  float r = rsqrtf(q * (1.0f / DMODEL) - m * m + 1e-5f);
  const float4* w4 = (const float4*)w;
  const float4* b4 = (const float4*)b;
  float4* o4 = (float4*)(out + (size_t)gw * DMODEL);
  float4 vv[3] = {v0, v1, v2};
  #pragma unroll
  for (int seg = 0; seg < 3; ++seg){
    float4 ww = w4[seg*64 + lane], bb = b4[seg*64 + lane], x = vv[seg], o;
    o.x = (x.x - m) * r * ww.x + bb.x;
    o.y = (x.y - m) * r * ww.y + bb.y;
    o.z = (x.z - m) * r * ww.z + bb.z;
    o.w = (x.w - m) * r * ww.w + bb.w;
    o4[seg*64 + lane] = o;
  }
}

// -------- wave-per-4-columns GEMM --------
template<int K, int NC, int ACT, bool RES>
__global__ __launch_bounds__(256) void k_gemmW(const float* __restrict__ A,
    const float* __restrict__ W, const float* __restrict__ bias,
    const float* __restrict__ res, float* __restrict__ out){
  int gw = (blockIdx.x * 256 + threadIdx.x) >> 6;
  int lane = threadIdx.x & 63;
  int sl = lane & 7, g = lane >> 3;
  int bg = gw & 7; int j0 = (gw >> 3) * 4;
  const float4* a4 = (const float4*)(A + (size_t)(bg*8 + g) * K);
  const float4* w0 = (const float4*)(W + (size_t)(j0+0) * K);
  const float4* w1 = (const float4*)(W + (size_t)(j0+1) * K);
  const float4* w2 = (const float4*)(W + (size_t)(j0+2) * K);
  const float4* w3 = (const float4*)(W + (size_t)(j0+3) * K);
  float acc0 = 0, acc1 = 0, acc2 = 0, acc3 = 0;
  #pragma unroll 4
  for (int i = 0; i < K/32; ++i){
    float4 av = a4[i*8 + sl];
    acc0 += dot4f(av, w0[i*8 + sl]);
    acc1 += dot4f(av, w1[i*8 + sl]);
    acc2 += dot4f(av, w2[i*8 + sl]);
    acc3 += dot4f(av, w3[i*8 + sl]);
  }
  #pragma unroll
  for (int o = 1; o <= 4; o <<= 1){
    acc0 += __shfl_xor(acc0, o, 64);
    acc1 += __shfl_xor(acc1, o, 64);
    acc2 += __shfl_xor(acc2, o, 64);
    acc3 += __shfl_xor(acc3, o, 64);
  }
  if (sl == 0){
    int row = bg*8 + g;
    float4 bj = *(const float4*)(bias + j0);
    float a[4] = {acc0, acc1, acc2, acc3};
    float bb[4] = {bj.x, bj.y, bj.z, bj.w};
    float v[4];
    #pragma unroll
    for (int u = 0; u < 4; ++u){
      float t = (ACT == 2) ? a[u] * (1.0f/3.0f) + bb[u] : a[u] + bb[u];
      if (ACT == 1) t = t / (1.0f + __expf(-t));
      v[u] = t;
    }
    size_t o = (size_t)row * NC + j0;
    if (RES){
      float4 rr = *(const float4*)(res + o);
      v[0] += rr.x; v[1] += rr.y; v[2] += rr.z; v[3] += rr.w;
    }
    *(float4*)(out + o) = make_float4(v[0], v[1], v[2], v[3]);
  }
}

// -------- fused query head: LN(ctx) + Wq proj + qproj (SC only; SQW obsolete) --------
__global__ __launch_bounds__(256) void k_qhead(const float* __restrict__ cur,
    const float* __restrict__ qn_w, const float* __restrict__ qn_b,
    const float* __restrict__ Wq, const float* __restrict__ bq,
    const float* __restrict__ Wk, const float* __restrict__ bk,
    const float* __restrict__ snw, const float* __restrict__ snb,
    uint32_t* __restrict__ QWbf, float* __restrict__ SC){
  __shared__ float qln_lds[DMODEL];
  __shared__ float qh_lds[256];
  __shared__ float red[8];
  int blk = blockIdx.x;
  int qq = blk & 3, b = blk >> 2;
  int tid = threadIdx.x, lane = tid & 63, wid = tid >> 6;
  if (qq == 3){
    int w16 = b*16 + 12 + wid;
    uint32_t* qwout = QWbf + (size_t)w16 * 384;
    #pragma unroll
    for (int k = 0; k < 6; ++k) qwout[k*64 + lane] = 0;
    if (lane == 0) SC[w16] = 0.0f;
    return;
  }
  // stage 1: LN row b
  {
    float x0 = cur[(size_t)b*DMODEL + tid];
    float x1 = cur[(size_t)b*DMODEL + 256 + tid];
    float x2 = cur[(size_t)b*DMODEL + 512 + tid];
    float s = x0 + x1 + x2;
    float q = x0*x0 + x1*x1 + x2*x2;
    s = wsum64(s); q = wsum64(q);
    if (lane == 0){ red[wid] = s; red[4 + wid] = q; }
    __syncthreads();
    float st = red[0] + red[1] + red[2] + red[3];
    float qt = red[4] + red[5] + red[6] + red[7];
    float m = st * (1.0f/DMODEL);
    float r = rsqrtf(qt * (1.0f/DMODEL) - m*m + 1e-5f);
    qln_lds[tid]       = (x0 - m)*r*qn_w[tid]       + qn_b[tid];
    qln_lds[256 + tid] = (x1 - m)*r*qn_w[256 + tid] + qn_b[256 + tid];
    qln_lds[512 + tid] = (x2 - m)*r*qn_w[512 + tid] + qn_b[512 + tid];
  }
  __syncthreads();
  // stage 2: qh col = qq*256 + tid
  {
    int col = qq*256 + tid;
    const float4* wr = (const float4*)(Wq + (size_t)col * DMODEL);
    const float4* ql = (const float4*)qln_lds;
    float acc = 0;
    #pragma unroll 8
    for (int i = 0; i < 192; ++i) acc += dot4f(ql[i], wr[i]);
    qh_lds[tid] = acc + bq[col];
  }
  __syncthreads();
  // stage 3: qpr for head hh = qq*4 + wid
  {
    int hh = qq*4 + wid;
    int w16 = b*16 + hh;
    const float* qrow = qh_lds + wid*64;
    const float* wbase = Wk + (size_t)hh * DHEAD * DMODEL;
    float qa[6] = {0,0,0,0,0,0}, qb[6] = {0,0,0,0,0,0};
    for (int e = 0; e < DHEAD; ++e){
      float qv = qrow[e];
      const float* wr = wbase + (size_t)e * DMODEL + 2*lane;
      #pragma unroll
      for (int k = 0; k < 6; ++k){
        qa[k] = fmaf(qv, wr[k*128], qa[k]);
        qb[k] = fmaf(qv, wr[k*128 + 1], qb[k]);
      }
    }
    uint32_t* qwout = QWbf + (size_t)w16 * 384;
    float s2 = 0;
    #pragma unroll
    for (int k = 0; k < 6; ++k){
      int d0 = k*128 + 2*lane;
      float va = qa[k] * snw[d0]   * 0.125f;
      float vb = qb[k] * snw[d0+1] * 0.125f;
      qwout[k*64 + lane] = bfpair(va, vb);
      s2 = fmaf(qa[k], snb[d0], fmaf(qb[k], snb[d0+1], s2));
    }
    float s3 = qrow[lane] * bk[hh*DHEAD + lane];
    s2 = wsum64(s2); s3 = wsum64(s3);
    if (lane == 0) SC[w16] = 0.125f * (s2 + s3);
  }
}

// -------- prep (once): write NORMALIZED rows x^ = (x-m)*r as bf16, len-gated --------
__global__ __launch_bounds__(256) void k_prep(const float* __restrict__ seq,
    const int* __restrict__ lens, uint32_t* __restrict__ xbf){
  int gw = (blockIdx.x * 256 + threadIdx.x) >> 6;
  int lane = threadIdx.x & 63;
  int nb = gw >> 9, s = gw & 511;
  if (s >= lens[nb]) return;
  const float4* x4 = (const float4*)(seq + (size_t)gw * DMODEL);
  float4 v0 = x4[lane], v1 = x4[64 + lane], v2 = x4[128 + lane];
  float sm = v0.x+v0.y+v0.z+v0.w + v1.x+v1.y+v1.z+v1.w + v2.x+v2.y+v2.z+v2.w;
  float q = dot4f(v0,v0) + dot4f(v1,v1) + dot4f(v2,v2);
  sm = wsum64(sm); q = wsum64(q);
  float m = sm * (1.0f/DMODEL);
  float r = rsqrtf(q * (1.0f/DMODEL) - m*m + 1e-5f);
  uint32_t* o = xbf + (size_t)gw * 384;
  o[2*lane]       = bfpair((v0.x-m)*r, (v0.y-m)*r);
  o[2*lane+1]     = bfpair((v0.z-m)*r, (v0.w-m)*r);
  o[128+2*lane]   = bfpair((v1.x-m)*r, (v1.y-m)*r);
  o[128+2*lane+1] = bfpair((v1.z-m)*r, (v1.w-m)*r);
  o[256+2*lane]   = bfpair((v2.x-m)*r, (v2.y-m)*r);
  o[256+2*lane+1] = bfpair((v2.z-m)*r, (v2.w-m)*r);
}

// -------- MFMA attention on normalized rows: score = QW.x^ + SC --------
__global__ __launch_bounds__(256) void k_attnM(const uint32_t* __restrict__ xbf,
    const int* __restrict__ lens, const uint32_t* __restrict__ QWbf,
    const float* __restrict__ SC,
    float* __restrict__ Pacc, float* __restrict__ Pden, float* __restrict__ Pmx){
  __shared__ float er_lds[64*17];
  __shared__ float tmax[4][16], tsum[4][16], fls[4][16];
  int blk = blockIdx.x;
  int ch = blk & 7, nb = blk >> 3;
  int len = lens[nb];
  int s0 = ch * ROWCH;
  if (s0 >= len) return;
  int b = nb % NB;
  int tid = threadIdx.x, wid = tid >> 6, lane = tid & 63;
  int l15 = lane & 15, mg = lane >> 4;
  int r0 = s0 + wid * 16;

  const short8* ax = (const short8*)(xbf + ((size_t)(nb*SEQLEN + r0 + l15)) * 384) + mg;
  const short8* bq = (const short8*)(QWbf + ((size_t)(b*16 + l15)) * 384) + mg;
  f32x4 acc = {0.0f, 0.0f, 0.0f, 0.0f};
  #pragma unroll
  for (int kk = 0; kk < 24; ++kk)
    acc = __builtin_amdgcn_mfma_f32_16x16x32_bf16(ax[kk*4], bq[kk*4], acc, 0, 0, 0);
  float scc = SC[b*16 + l15];
  float sco[4];
  #pragma unroll
  for (int j = 0; j < 4; ++j){
    int s = r0 + mg*4 + j;
    sco[j] = (s < len) ? acc[j] + scc : -3.0e38f;
  }
  float tm = fmaxf(fmaxf(sco[0], sco[1]), fmaxf(sco[2], sco[3]));
  tm = fmaxf(tm, __shfl_xor(tm, 16, 64));
  tm = fmaxf(tm, __shfl_xor(tm, 32, 64));
  float es = 0;
  #pragma unroll
  for (int j = 0; j < 4; ++j){
    float e = (sco[j] > -1.0e37f) ? __expf(sco[j] - tm) : 0.0f;
    er_lds[(wid*16 + mg*4 + j)*17 + l15] = e;
    es += e;
  }
  es += __shfl_xor(es, 16, 64); es += __shfl_xor(es, 32, 64);
  if (lane < 16){ tmax[wid][lane] = tm; tsum[wid][lane] = es; }
  __syncthreads();
  if (tid < 16){
    int hh = tid;
    float M = fmaxf(fmaxf(tmax[0][hh], tmax[1][hh]), fmaxf(tmax[2][hh], tmax[3][hh]));
    float D = 0;
    #pragma unroll
    for (int w = 0; w < 4; ++w){
      float f = (tmax[w][hh] > -1.0e37f) ? __expf(tmax[w][hh] - M) : 0.0f;
      fls[w][hh] = f;
      D = fmaf(f, tsum[w][hh], D);
    }
    if (hh < NHEAD){
      Pmx[(size_t)blk*NHEAD + hh] = M;
      Pden[(size_t)blk*NHEAD + hh] = D;
    }
  }
  __syncthreads();
  #pragma unroll
  for (int t = 0; t < 4; ++t){
    int i = tid + t*256;
    int row = i >> 4, hh = i & 15;
    er_lds[row*17 + hh] *= fls[row >> 4][hh];
  }
  __syncthreads();

  int h0 = wid * 3;
  float a[3][12];
  #pragma unroll
  for (int j = 0; j < 3; ++j)
    #pragma unroll
    for (int c = 0; c < 12; ++c) a[j][c] = 0.0f;
  const uint32_t* xr0 = xbf + ((size_t)(nb*SEQLEN + s0)) * 384 + lane*6;
  int nrows = len - s0; if (nrows > ROWCH) nrows = ROWCH;
  for (int s = 0; s < nrows; ++s){
    const uint32_t* xr = xr0 + (size_t)s * 384;
    uint2 u01 = *(const uint2*)(xr);
    uint2 u23 = *(const uint2*)(xr + 2);
    uint2 u45 = *(const uint2*)(xr + 4);
    float e0 = er_lds[s*17 + h0], e1 = er_lds[s*17 + h0 + 1], e2 = er_lds[s*17 + h0 + 2];
    float x[12];
    x[0]  = __uint_as_float(u01.x << 16); x[1]  = __uint_as_float(u01.x & 0xFFFF0000u);
    x[2]  = __uint_as_float(u01.y << 16); x[3]  = __uint_as_float(u01.y & 0xFFFF0000u);
    x[4]  = __uint_as_float(u23.x << 16); x[5]  = __uint_as_float(u23.x & 0xFFFF0000u);
    x[6]  = __uint_as_float(u23.y << 16); x[7]  = __uint_as_float(u23.y & 0xFFFF0000u);
    x[8]  = __uint_as_float(u45.x << 16); x[9]  = __uint_as_float(u45.x & 0xFFFF0000u);
    x[10] = __uint_as_float(u45.y << 16); x[11] = __uint_as_float(u45.y & 0xFFFF0000u);
    #pragma unroll
    for (int c = 0; c < 12; ++c){
      a[0][c] = fmaf(e0, x[c], a[0][c]);
      a[1][c] = fmaf(e1, x[c], a[1][c]);
      a[2][c] = fmaf(e2, x[c], a[2][c]);
    }
  }
  #pragma unroll
  for (int j = 0; j < 3; ++j){
    float* p = Pacc + ((size_t)blk*NHEAD + h0 + j) * DMODEL + lane*12;
    #pragma unroll
    for (int c = 0; c < 12; c += 4)
      *(float4*)(p + c) = make_float4(a[j][c], a[j][c+1], a[j][c+2], a[j][c+3]);
  }
}

// -------- fused combine + Wv projection: block = (h, b) --------
// Builds wctx row (b,h) in LDS (softmax-merged over chunks+domains, + seq-LN affine),
// then ctxsum[b, h*64 .. h*64+64) = wrow . Wv[he] + 3*bv[he].
__global__ __launch_bounds__(256) void k_cvf(const float* __restrict__ Pacc,
    const float* __restrict__ Pden, const float* __restrict__ Pmx,
    const int* __restrict__ lens, const float* __restrict__ snw,
    const float* __restrict__ snb, const float* __restrict__ Wv,
    const float* __restrict__ bv, float* __restrict__ ctxsum){
  __shared__ float wrow[DMODEL];
  int blk = blockIdx.x;
  int h = blk >> 6, b = blk & 63;
  int tid = threadIdx.x;
  float vec[3] = {0.0f, 0.0f, 0.0f};
  #pragma unroll
  for (int n = 0; n < NDOM; ++n){
    int nb = n*NB + b;
    int len = lens[nb];
    int na = (len + ROWCH - 1) >> 6; if (na > NCH) na = NCH;
    size_t p0 = (size_t)(nb * NCH) * NHEAD + h;
    float M = -3.0e38f;
    for (int c = 0; c < na; ++c) M = fmaxf(M, Pmx[p0 + (size_t)c*NHEAD]);
    float D = 0;
    for (int c = 0; c < na; ++c)
      D = fmaf(__expf(Pmx[p0 + (size_t)c*NHEAD] - M), Pden[p0 + (size_t)c*NHEAD], D);
    float inv = 1.0f / D;
    for (int c = 0; c < na; ++c){
      size_t pi = p0 + (size_t)c*NHEAD;
      float w = __expf(Pmx[pi] - M) * inv;
      const float* pa = Pacc + pi*DMODEL + tid*3;
      vec[0] = fmaf(w, pa[0], vec[0]);
      vec[1] = fmaf(w, pa[1], vec[1]);
      vec[2] = fmaf(w, pa[2], vec[2]);
    }
  }
  #pragma unroll
  for (int u = 0; u < 3; ++u){
    int d = tid*3 + u;
    wrow[d] = vec[u] * snw[d] + 3.0f * snb[d];
  }
  __syncthreads();
  int lane = tid & 63, wid = tid >> 6;
  int sl = lane & 7, g8 = lane >> 3;
  const float4* wr4 = (const float4*)wrow;
  #pragma unroll
  for (int it = 0; it < 2; ++it){
    int he = (h << 6) + wid*16 + it*8 + g8;
    const float4* v4 = (const float4*)(Wv + (size_t)he * DMODEL);
    float acc = 0;
    #pragma unroll 4
    for (int i = 0; i < 12; ++i) acc += dot4f(wr4[i*8 + sl], v4[i*8 + sl]);
    acc += __shfl_xor(acc, 1, 64);
    acc += __shfl_xor(acc, 2, 64);
    acc += __shfl_xor(acc, 4, 64);
    if (sl == 0) ctxsum[(size_t)b * DMODEL + he] = acc + 3.0f * bv[he];
  }
}

// -------- gate + residual --------
__global__ __launch_bounds__(256) void k_gate2(const float* __restrict__ ctx,
    const float* __restrict__ sctx, const float* __restrict__ Wg,
    const float* __restrict__ gb, float* __restrict__ out){
  int gw = (blockIdx.x * 256 + threadIdx.x) >> 6;
  int lane = threadIdx.x & 63;
  int sl = lane & 7, g = lane >> 3;
  int bg = gw & 7; int j0 = (gw >> 3) * 4;
  int row = bg*8 + g;
  const float4* c4 = (const float4*)(ctx + (size_t)row * DMODEL);
  const float4* s4 = (const float4*)(sctx + (size_t)row * DMODEL);
  const float4* wr0 = (const float4*)(Wg + (size_t)(j0+0) * 2 * DMODEL);
  const float4* wr1 = (const float4*)(Wg + (size_t)(j0+1) * 2 * DMODEL);
  const float4* wr2 = (const float4*)(Wg + (size_t)(j0+2) * 2 * DMODEL);
  const float4* wr3 = (const float4*)(Wg + (size_t)(j0+3) * 2 * DMODEL);
  float acc0 = 0, acc1 = 0, acc2 = 0, acc3 = 0;
  #pragma unroll 4
  for (int i = 0; i < DMODEL/32; ++i){
    float4 cv = c4[i*8 + sl], sv = s4[i*8 + sl];
    acc0 += dot4f(cv, wr0[i*8 + sl]) + dot4f(sv, wr0[192 + i*8 + sl]);
    acc1 += dot4f(cv, wr1[i*8 + sl]) + dot4f(sv, wr1[192 + i*8 + sl]);
    acc2 += dot4f(cv, wr2[i*8 + sl]) + dot4f(sv, wr2[192 + i*8 + sl]);
    acc3 += dot4f(cv, wr3[i*8 + sl]) + dot4f(sv, wr3[192 + i*8 + sl]);
  }
  #pragma unroll
  for (int o = 1; o <= 4; o <<= 1){
    acc0 += __shfl_xor(acc0, o, 64);
    acc1 += __shfl_xor(acc1, o, 64);
    acc2 += __shfl_xor(acc2, o, 64);
    acc3 += __shfl_xor(acc3, o, 64);
  }
  if (sl == 0){
    size_t o = (size_t)row * DMODEL + j0;
    float4 bb = *(const float4*)(gb + j0);
    float4 cc = *(const float4*)(ctx + o);
    float4 ss = *(const float4*)(sctx + o);
    float4 v;
    v.x = cc.x + ss.x / (1.0f + __expf(-(acc0 + bb.x)));
    v.y = cc.y + ss.y / (1.0f + __expf(-(acc1 + bb.y)));
    v.z = cc.z + ss.z / (1.0f + __expf(-(acc2 + bb.z)));
    v.w = cc.w + ss.w / (1.0f + __expf(-(acc3 + bb.w)));
    *(float4*)(out + o) = v;
  }
}

// -------- fused classifier tail part 1: double-LN + FFN1 + weighted partial sum --------
// block = (b, jchunk of 768); part[blk] = sum_{j in chunk} silu(h0 . cw1[j] + cb1[j]) * cw2[j]
__global__ __launch_bounds__(256) void k_tail1(const float* __restrict__ cur,
    const float* __restrict__ on_w, const float* __restrict__ on_b,
    const float* __restrict__ cl_w, const float* __restrict__ cl_b,
    const float* __restrict__ cw1, const float* __restrict__ cb1,
    const float* __restrict__ cw2, float* __restrict__ part){
  __shared__ float h0s[DMODEL];
  __shared__ float red[16];
  int blk = blockIdx.x;
  int b = blk >> 2, ch = blk & 3;
  int tid = threadIdx.x, lane = tid & 63, wid = tid >> 6;
  float x0 = cur[(size_t)b*DMODEL + tid];
  float x1 = cur[(size_t)b*DMODEL + 256 + tid];
  float x2 = cur[(size_t)b*DMODEL + 512 + tid];
  float s = x0 + x1 + x2, q = x0*x0 + x1*x1 + x2*x2;
  s = wsum64(s); q = wsum64(q);
  if (lane == 0){ red[wid] = s; red[4 + wid] = q; }
  __syncthreads();
  float st = red[0] + red[1] + red[2] + red[3];
  float qt = red[4] + red[5] + red[6] + red[7];
  float m = st * (1.0f/DMODEL);
  float r = rsqrtf(qt * (1.0f/DMODEL) - m*m + 1e-5f);
  float y0 = (x0 - m)*r*on_w[tid]       + on_b[tid];
  float y1 = (x1 - m)*r*on_w[256 + tid] + on_b[256 + tid];
  float y2 = (x2 - m)*r*on_w[512 + tid] + on_b[512 + tid];
  float s2 = y0 + y1 + y2, q2 = y0*y0 + y1*y1 + y2*y2;
  s2 = wsum64(s2); q2 = wsum64(q2);
  if (lane == 0){ red[8 + wid] = s2; red[12 + wid] = q2; }
  __syncthreads();
  float st2 = red[8] + red[9] + red[10] + red[11];
  float qt2 = red[12] + red[13] + red[14] + red[15];
  float m2 = st2 * (1.0f/DMODEL);
  float r2 = rsqrtf(qt2 * (1.0f/DMODEL) - m2*m2 + 1e-5f);
  h0s[tid]       = (y0 - m2)*r2*cl_w[tid]       + cl_b[tid];
  h0s[256 + tid] = (y1 - m2)*r2*cl_w[256 + tid] + cl_b[256 + tid];
  h0s[512 + tid] = (y2 - m2)*r2*cl_w[512 + tid] + cl_b[512 + tid];
  __syncthreads();
  // GEMM+reduce phase: wave wid covers 192 j's, 8 at a time
  int sl = lane & 7, g8 = lane >> 3;
  int jb = ch*768 + wid*192;
  const float4* h4 = (const float4*)h0s;
  float pt = 0;
  for (int ii = 0; ii < 24; ++ii){
    int j = jb + ii*8 + g8;
    const float4* w4 = (const float4*)(cw1 + (size_t)j * DMODEL);
    float acc = 0;
    #pragma unroll 4
    for (int i = 0; i < 24; ++i) acc += dot4f(h4[i*8 + sl], w4[i*8 + sl]);
    acc += __shfl_xor(acc, 1, 64);
    acc += __shfl_xor(acc, 2, 64);
    acc += __shfl_xor(acc, 4, 64);
    if (sl == 0){
      float t = acc + cb1[j];
      t = t / (1.0f + __expf(-t));
      pt = fmaf(t, cw2[j], pt);
    }
  }
  pt = wsum64(pt);
  __syncthreads();
  if (lane == 0) red[wid] = pt;
  __syncthreads();
  if (tid == 0) part[blk] = red[0] + red[1] + red[2] + red[3];
}

// -------- tail part 2: out[b] = sum of 4 partials + cb2 --------
__global__ __launch_bounds__(64) void k_tail2(const float* __restrict__ part,
    const float* __restrict__ b2, float* __restrict__ out){
  int b = threadIdx.x;
  out[b] = part[b*4] + part[b*4+1] + part[b*4+2] + part[b*4+3] + b2[0];
}

extern "C" void kernel_launch(void* const* d_in, const int* in_sizes, int n_in,
                              void* d_out, int out_size, void* d_ws, size_t ws_size,
                              hipStream_t stream){
  const float* in_ctx = (const float*)d_in[0];
  const float* seq    = (const float*)d_in[1];
  const int*   lens   = (const int*)d_in[2];
  const float* qn_w   = (const float*)d_in[3];
  const float* qn_b   = (const float*)d_in[4];
  const float* sn_w   = (const float*)d_in[5];
  const float* sn_b   = (const float*)d_in[6];
  const float* in_w   = (const float*)d_in[7];
  const float* in_b   = (const float*)d_in[8];
  const float* out_w  = (const float*)d_in[9];
  const float* out_b  = (const float*)d_in[10];
  const float* gate_w = (const float*)d_in[11];
  const float* gate_b = (const float*)d_in[12];
  const float* fln_w  = (const float*)d_in[13];
  const float* fln_b  = (const float*)d_in[14];
  const float* fw1    = (const float*)d_in[15];
  const float* fb1    = (const float*)d_in[16];
  const float* fw2    = (const float*)d_in[17];
  const float* fb2    = (const float*)d_in[18];
  const float* on_w   = (const float*)d_in[19];
  const float* on_b   = (const float*)d_in[20];
  const float* cl_w   = (const float*)d_in[21];
  const float* cl_b   = (const float*)d_in[22];
  const float* cw1    = (const float*)d_in[23];
  const float* cb1    = (const float*)d_in[24];
  const float* cw2    = (const float*)d_in[25];
  const float* cb2    = (const float*)d_in[26];

  float* wsf = (float*)d_ws;
  size_t off = 0;
  auto alloc = [&](size_t n){ float* p = wsf + off; off += n; return p; };
  float* c0     = alloc((size_t)NB*DMODEL);
  float* c1     = alloc((size_t)NB*DMODEL);
  float* cmid   = alloc((size_t)NB*DMODEL);
  uint32_t* QWbf = (uint32_t*)alloc((size_t)NB*16*384);
  float* SCb    = alloc((size_t)NB*16);
  uint32_t* xbf = (uint32_t*)alloc((size_t)NBROWS*SEQLEN*384);
  float* Pacc   = alloc((size_t)NBROWS*NCH*NHEAD*DMODEL);
  float* Pden   = alloc((size_t)NBROWS*NCH*NHEAD);
  float* Pmx    = alloc((size_t)NBROWS*NCH*NHEAD);
  float* ctxsum = alloc((size_t)NB*DMODEL);
  float* sctx   = alloc((size_t)NB*DMODEL);
  float* h0     = alloc((size_t)NB*DMODEL);
  float* h1     = alloc((size_t)NB*FFNH);
  float* part   = alloc(256);
  (void)ws_size; (void)in_sizes; (void)n_in; (void)out_size;

  hipMemcpyAsync(c0, in_ctx, (size_t)NB*DMODEL*sizeof(float), hipMemcpyDeviceToDevice, stream);
  k_prep<<<(NBROWS*SEQLEN)/4, 256, 0, stream>>>(seq, lens, xbf);

  float* cur = c0; float* nxt = c1;
  for (int l = 0; l < NBLK; ++l){
    const float* Wq = in_w + (size_t)l * 3 * DMODEL * DMODEL;
    const float* Wk = Wq + (size_t)DMODEL * DMODEL;
    const float* Wv = Wq + (size_t)2 * DMODEL * DMODEL;
    const float* bq = in_b + (size_t)l * 3 * DMODEL;
    const float* bk = bq + DMODEL;
    const float* bv = bq + 2 * DMODEL;

    k_qhead<<<256, 256, 0, stream>>>(cur, qn_w + l*DMODEL, qn_b + l*DMODEL,
        Wq, bq, Wk, bk, sn_w + l*DMODEL, sn_b + l*DMODEL, QWbf, SCb);
    k_attnM<<<NBROWS*NCH, 256, 0, stream>>>(xbf, lens, QWbf, SCb, Pacc, Pden, Pmx);
    k_cvf<<<NHEAD*NB, 256, 0, stream>>>(Pacc, Pden, Pmx, lens, sn_w + l*DMODEL, sn_b + l*DMODEL, Wv, bv, ctxsum);
    k_gemmW<DMODEL,DMODEL,2,false><<<384, 256, 0, stream>>>(ctxsum, out_w + (size_t)l*DMODEL*DMODEL, out_b + l*DMODEL, nullptr, sctx);
    k_gate2<<<384, 256, 0, stream>>>(cur, sctx, gate_w + (size_t)l*DMODEL*2*DMODEL, gate_b + l*DMODEL, cmid);
    k_ln<<<16, 256, 0, stream>>>(cmid, fln_w + l*DMODEL, fln_b + l*DMODEL, h0, NB);
    k_gemmW<DMODEL,FFNH,1,false><<<1536, 256, 0, stream>>>(h0, fw1 + (size_t)l*FFNH*DMODEL, fb1 + l*FFNH, nullptr, h1);
    k_gemmW<FFNH,DMODEL,0,true><<<384, 256, 0, stream>>>(h1, fw2 + (size_t)l*DMODEL*FFNH, fb2 + l*DMODEL, cmid, nxt);
    float* t = cur; cur = nxt; nxt = t;
  }

  k_tail1<<<256, 256, 0, stream>>>(cur, on_w, on_b, cl_w, cl_b, cw1, cb1, cw2, part);
  k_tail2<<<1, 64, 0, stream>>>(part, cb2, (float*)d_out);
}

// Round 12
// 563.288 us; speedup vs baseline: 1.0160x; 1.0160x over previous
//
#include <hip/hip_runtime.h>
#include <hip/hip_bf16.h>
#include <cstdint>

#define DMODEL 768
#define NB 64
#define NHEAD 12
#define DHEAD 64
#define SEQLEN 512
#define NDOM 3
#define NBLK 2
#define FFNH 3072
#define NBROWS (NDOM*NB)   // 192
#define NCH 8              // 64-row chunks
#define ROWCH 64

typedef __attribute__((ext_vector_type(8))) short short8;
typedef __attribute__((ext_vector_type(4))) float f32x4;

__device__ __forceinline__ float wsum64(float v){
  #pragma unroll
  for (int o = 32; o; o >>= 1) v += __shfl_xor(v, o, 64);
  return v;
}
__device__ __forceinline__ float dot4f(float4 a, float4 b){
  return fmaf(a.x, b.x, fmaf(a.y, b.y, fmaf(a.z, b.z, a.w * b.w)));
}
__device__ __forceinline__ uint32_t bfpair(float lo, float hi){
  uint32_t ul = __float_as_uint(lo), uh = __float_as_uint(hi);
  ul = (ul + 0x7FFFu + ((ul >> 16) & 1u)) >> 16;
  uh = (uh + 0x7FFFu + ((uh >> 16) & 1u)) & 0xFFFF0000u;
  return ul | uh;
}
__device__ __forceinline__ float4 ubf4(uint2 u){
  return make_float4(__uint_as_float(u.x << 16), __uint_as_float(u.x & 0xFFFF0000u),
                     __uint_as_float(u.y << 16), __uint_as_float(u.y & 0xFFFF0000u));
}

// -------- weight fp32 -> bf16-pair conversion (one-time) --------
__global__ __launch_bounds__(256) void k_w2bf(const float* __restrict__ in,
    uint32_t* __restrict__ out, int n){
  int i = blockIdx.x * 256 + threadIdx.x;
  if (i >= n) return;
  float2 v = *(const float2*)(in + 2*(size_t)i);
  out[i] = bfpair(v.x, v.y);
}

// -------- LayerNorm: one wave per row --------
__global__ __launch_bounds__(256) void k_ln(const float* __restrict__ in,
    const float* __restrict__ w, const float* __restrict__ b,
    float* __restrict__ out, int rows){
  int gw = (blockIdx.x * 256 + threadIdx.x) >> 6;
  int lane = threadIdx.x & 63;
  if (gw >= rows) return;
  const float4* x4 = (const float4*)(in + (size_t)gw * DMODEL);
  float4 v0 = x4[lane], v1 = x4[64 + lane], v2 = x4[128 + lane];
  float s = v0.x+v0.y+v0.z+v0.w + v1.x+v1.y+v1.z+v1.w + v2.x+v2.y+v2.z+v2.w;
  float q = dot4f(v0,v0) + dot4f(v1,v1) + dot4f(v2,v2);
  s = wsum64(s); q = wsum64(q);
  float m = s * (1.0f / DMODEL);
  float r = rsqrtf(q * (1.0f / DMODEL) - m * m + 1e-5f);
  const float4* w4 = (const float4*)w;
  const float4* b4 = (const float4*)b;
  float4* o4 = (float4*)(out + (size_t)gw * DMODEL);
  float4 vv[3] = {v0, v1, v2};
  #pragma unroll
  for (int seg = 0; seg < 3; ++seg){
    float4 ww = w4[seg*64 + lane], bb = b4[seg*64 + lane], x = vv[seg], o;
    o.x = (x.x - m) * r * ww.x + bb.x;
    o.y = (x.y - m) * r * ww.y + bb.y;
    o.z = (x.z - m) * r * ww.z + bb.z;
    o.w = (x.w - m) * r * ww.w + bb.w;
    o4[seg*64 + lane] = o;
  }
}

// -------- double LayerNorm --------
__global__ __launch_bounds__(256) void k_ln2(const float* __restrict__ in,
    const float* __restrict__ w1, const float* __restrict__ b1,
    const float* __restrict__ w2, const float* __restrict__ b2,
    float* __restrict__ out, int rows){
  int gw = (blockIdx.x * 256 + threadIdx.x) >> 6;
  int lane = threadIdx.x & 63;
  if (gw >= rows) return;
  const float4* x4 = (const float4*)(in + (size_t)gw * DMODEL);
  float4 vv[3] = {x4[lane], x4[64 + lane], x4[128 + lane]};
  float s = 0, q = 0;
  #pragma unroll
  for (int g = 0; g < 3; ++g){ s += vv[g].x+vv[g].y+vv[g].z+vv[g].w; q += dot4f(vv[g], vv[g]); }
  s = wsum64(s); q = wsum64(q);
  float m = s * (1.0f/DMODEL);
  float r = rsqrtf(q * (1.0f/DMODEL) - m*m + 1e-5f);
  const float4* w14 = (const float4*)w1; const float4* b14 = (const float4*)b1;
  float4 yy[3]; float s2 = 0, q2 = 0;
  #pragma unroll
  for (int g = 0; g < 3; ++g){
    float4 ww = w14[g*64 + lane], bb = b14[g*64 + lane], x = vv[g], o;
    o.x = (x.x-m)*r*ww.x + bb.x; o.y = (x.y-m)*r*ww.y + bb.y;
    o.z = (x.z-m)*r*ww.z + bb.z; o.w = (x.w-m)*r*ww.w + bb.w;
    yy[g] = o; s2 += o.x+o.y+o.z+o.w; q2 += dot4f(o,o);
  }
  s2 = wsum64(s2); q2 = wsum64(q2);
  float m2 = s2 * (1.0f/DMODEL);
  float r2 = rsqrtf(q2 * (1.0f/DMODEL) - m2*m2 + 1e-5f);
  const float4* w24 = (const float4*)w2; const float4* b24 = (const float4*)b2;
  float4* o4 = (float4*)(out + (size_t)gw * DMODEL);
  #pragma unroll
  for (int g = 0; g < 3; ++g){
    float4 ww = w24[g*64 + lane], bb = b24[g*64 + lane], y = yy[g], o;
    o.x = (y.x-m2)*r2*ww.x + bb.x; o.y = (y.y-m2)*r2*ww.y + bb.y;
    o.z = (y.z-m2)*r2*ww.z + bb.z; o.w = (y.w-m2)*r2*ww.w + bb.w;
    o4[g*64 + lane] = o;
  }
}

// -------- wave-per-4-columns GEMM (fp32 weights) --------
template<int K, int NC, int ACT, bool RES>
__global__ __launch_bounds__(256) void k_gemmW(const float* __restrict__ A,
    const float* __restrict__ W, const float* __restrict__ bias,
    const float* __restrict__ res, float* __restrict__ out){
  int gw = (blockIdx.x * 256 + threadIdx.x) >> 6;
  int lane = threadIdx.x & 63;
  int sl = lane & 7, g = lane >> 3;
  int bg = gw & 7; int j0 = (gw >> 3) * 4;
  const float4* a4 = (const float4*)(A + (size_t)(bg*8 + g) * K);
  const float4* w0 = (const float4*)(W + (size_t)(j0+0) * K);
  const float4* w1 = (const float4*)(W + (size_t)(j0+1) * K);
  const float4* w2 = (const float4*)(W + (size_t)(j0+2) * K);
  const float4* w3 = (const float4*)(W + (size_t)(j0+3) * K);
  float acc0 = 0, acc1 = 0, acc2 = 0, acc3 = 0;
  #pragma unroll 4
  for (int i = 0; i < K/32; ++i){
    float4 av = a4[i*8 + sl];
    acc0 += dot4f(av, w0[i*8 + sl]);
    acc1 += dot4f(av, w1[i*8 + sl]);
    acc2 += dot4f(av, w2[i*8 + sl]);
    acc3 += dot4f(av, w3[i*8 + sl]);
  }
  #pragma unroll
  for (int o = 1; o <= 4; o <<= 1){
    acc0 += __shfl_xor(acc0, o, 64);
    acc1 += __shfl_xor(acc1, o, 64);
    acc2 += __shfl_xor(acc2, o, 64);
    acc3 += __shfl_xor(acc3, o, 64);
  }
  if (sl == 0){
    int row = bg*8 + g;
    float4 bj = *(const float4*)(bias + j0);
    float a[4] = {acc0, acc1, acc2, acc3};
    float bb[4] = {bj.x, bj.y, bj.z, bj.w};
    float v[4];
    #pragma unroll
    for (int u = 0; u < 4; ++u){
      float t = (ACT == 2) ? a[u] * (1.0f/3.0f) + bb[u] : a[u] + bb[u];
      if (ACT == 1) t = t / (1.0f + __expf(-t));
      v[u] = t;
    }
    size_t o = (size_t)row * NC + j0;
    if (RES){
      float4 rr = *(const float4*)(res + o);
      v[0] += rr.x; v[1] += rr.y; v[2] += rr.z; v[3] += rr.w;
    }
    *(float4*)(out + o) = make_float4(v[0], v[1], v[2], v[3]);
  }
}

// -------- wave-per-4-columns GEMM (bf16 weights, fp32 activations/accum) --------
template<int K, int NC, int ACT, bool RES>
__global__ __launch_bounds__(256) void k_gemmWbf(const float* __restrict__ A,
    const uint32_t* __restrict__ W, const float* __restrict__ bias,
    const float* __restrict__ res, float* __restrict__ out){
  int gw = (blockIdx.x * 256 + threadIdx.x) >> 6;
  int lane = threadIdx.x & 63;
  int sl = lane & 7, g = lane >> 3;
  int bg = gw & 7; int j0 = (gw >> 3) * 4;
  const float4* a4 = (const float4*)(A + (size_t)(bg*8 + g) * K);
  const uint2* w0 = (const uint2*)(W + (size_t)(j0+0) * (K/2));
  const uint2* w1 = (const uint2*)(W + (size_t)(j0+1) * (K/2));
  const uint2* w2 = (const uint2*)(W + (size_t)(j0+2) * (K/2));
  const uint2* w3 = (const uint2*)(W + (size_t)(j0+3) * (K/2));
  float acc0 = 0, acc1 = 0, acc2 = 0, acc3 = 0;
  #pragma unroll 4
  for (int i = 0; i < K/32; ++i){
    float4 av = a4[i*8 + sl];
    acc0 += dot4f(av, ubf4(w0[i*8 + sl]));
    acc1 += dot4f(av, ubf4(w1[i*8 + sl]));
    acc2 += dot4f(av, ubf4(w2[i*8 + sl]));
    acc3 += dot4f(av, ubf4(w3[i*8 + sl]));
  }
  #pragma unroll
  for (int o = 1; o <= 4; o <<= 1){
    acc0 += __shfl_xor(acc0, o, 64);
    acc1 += __shfl_xor(acc1, o, 64);
    acc2 += __shfl_xor(acc2, o, 64);
    acc3 += __shfl_xor(acc3, o, 64);
  }
  if (sl == 0){
    int row = bg*8 + g;
    float4 bj = *(const float4*)(bias + j0);
    float a[4] = {acc0, acc1, acc2, acc3};
    float bb[4] = {bj.x, bj.y, bj.z, bj.w};
    float v[4];
    #pragma unroll
    for (int u = 0; u < 4; ++u){
      float t = (ACT == 2) ? a[u] * (1.0f/3.0f) + bb[u] : a[u] + bb[u];
      if (ACT == 1) t = t / (1.0f + __expf(-t));
      v[u] = t;
    }
    size_t o = (size_t)row * NC + j0;
    if (RES){
      float4 rr = *(const float4*)(res + o);
      v[0] += rr.x; v[1] += rr.y; v[2] += rr.z; v[3] += rr.w;
    }
    *(float4*)(out + o) = make_float4(v[0], v[1], v[2], v[3]);
  }
}

// -------- fused query head: LN(ctx) + Wq proj + qproj/reductions --------
__global__ __launch_bounds__(256) void k_qhead(const float* __restrict__ cur,
    const float* __restrict__ qn_w, const float* __restrict__ qn_b,
    const float* __restrict__ Wq, const float* __restrict__ bq,
    const float* __restrict__ Wk, const float* __restrict__ bk,
    const float* __restrict__ snw, const float* __restrict__ snb,
    uint32_t* __restrict__ QWbf, float* __restrict__ SQW, float* __restrict__ SC){
  __shared__ float qln_lds[DMODEL];
  __shared__ float qh_lds[256];
  __shared__ float red[8];
  int blk = blockIdx.x;
  int qq = blk & 3, b = blk >> 2;
  int tid = threadIdx.x, lane = tid & 63, wid = tid >> 6;
  if (qq == 3){
    int w16 = b*16 + 12 + wid;
    uint32_t* qwout = QWbf + (size_t)w16 * 384;
    #pragma unroll
    for (int k = 0; k < 6; ++k) qwout[k*64 + lane] = 0;
    if (lane == 0){ SQW[w16] = 0.0f; SC[w16] = 0.0f; }
    return;
  }
  // stage 1: LN row b
  {
    float x0 = cur[(size_t)b*DMODEL + tid];
    float x1 = cur[(size_t)b*DMODEL + 256 + tid];
    float x2 = cur[(size_t)b*DMODEL + 512 + tid];
    float s = x0 + x1 + x2;
    float q = x0*x0 + x1*x1 + x2*x2;
    s = wsum64(s); q = wsum64(q);
    if (lane == 0){ red[wid] = s; red[4 + wid] = q; }
    __syncthreads();
    float st = red[0] + red[1] + red[2] + red[3];
    float qt = red[4] + red[5] + red[6] + red[7];
    float m = st * (1.0f/DMODEL);
    float r = rsqrtf(qt * (1.0f/DMODEL) - m*m + 1e-5f);
    qln_lds[tid]       = (x0 - m)*r*qn_w[tid]       + qn_b[tid];
    qln_lds[256 + tid] = (x1 - m)*r*qn_w[256 + tid] + qn_b[256 + tid];
    qln_lds[512 + tid] = (x2 - m)*r*qn_w[512 + tid] + qn_b[512 + tid];
  }
  __syncthreads();
  // stage 2: qh col = qq*256 + tid
  {
    int col = qq*256 + tid;
    const float4* wr = (const float4*)(Wq + (size_t)col * DMODEL);
    const float4* ql = (const float4*)qln_lds;
    float acc = 0;
    #pragma unroll 8
    for (int i = 0; i < 192; ++i) acc += dot4f(ql[i], wr[i]);
    qh_lds[tid] = acc + bq[col];
  }
  __syncthreads();
  // stage 3: qpr for head hh = qq*4 + wid
  {
    int hh = qq*4 + wid;
    int w16 = b*16 + hh;
    const float* qrow = qh_lds + wid*64;
    const float* wbase = Wk + (size_t)hh * DHEAD * DMODEL;
    float qa[6] = {0,0,0,0,0,0}, qb[6] = {0,0,0,0,0,0};
    for (int e = 0; e < DHEAD; ++e){
      float qv = qrow[e];
      const float* wr = wbase + (size_t)e * DMODEL + 2*lane;
      #pragma unroll
      for (int k = 0; k < 6; ++k){
        qa[k] = fmaf(qv, wr[k*128], qa[k]);
        qb[k] = fmaf(qv, wr[k*128 + 1], qb[k]);
      }
    }
    uint32_t* qwout = QWbf + (size_t)w16 * 384;
    float s1 = 0, s2 = 0;
    #pragma unroll
    for (int k = 0; k < 6; ++k){
      int d0 = k*128 + 2*lane;
      float va = qa[k] * snw[d0]   * 0.125f;
      float vb = qb[k] * snw[d0+1] * 0.125f;
      uint32_t pr = bfpair(va, vb);
      qwout[k*64 + lane] = pr;
      s1 += __uint_as_float(pr << 16) + __uint_as_float(pr & 0xFFFF0000u);
      s2 = fmaf(qa[k], snb[d0], fmaf(qb[k], snb[d0+1], s2));
    }
    float s3 = qrow[lane] * bk[hh*DHEAD + lane];
    s1 = wsum64(s1); s2 = wsum64(s2); s3 = wsum64(s3);
    if (lane == 0){ SQW[w16] = s1; SC[w16] = 0.125f * (s2 + s3); }
  }
}

// -------- prep (once): LN stats + bf16 copy, len-gated --------
__global__ __launch_bounds__(256) void k_prep(const float* __restrict__ seq,
    const int* __restrict__ lens, uint32_t* __restrict__ xbf,
    float* __restrict__ mstat, float* __restrict__ rstat){
  int gw = (blockIdx.x * 256 + threadIdx.x) >> 6;
  int lane = threadIdx.x & 63;
  int nb = gw >> 9, s = gw & 511;
  if (s >= lens[nb]) return;
  const float4* x4 = (const float4*)(seq + (size_t)gw * DMODEL);
  float4 v0 = x4[lane], v1 = x4[64 + lane], v2 = x4[128 + lane];
  float sm = v0.x+v0.y+v0.z+v0.w + v1.x+v1.y+v1.z+v1.w + v2.x+v2.y+v2.z+v2.w;
  float q = dot4f(v0,v0) + dot4f(v1,v1) + dot4f(v2,v2);
  sm = wsum64(sm); q = wsum64(q);
  float m = sm * (1.0f/DMODEL);
  float r = rsqrtf(q * (1.0f/DMODEL) - m*m + 1e-5f);
  if (lane == 0){ mstat[gw] = m; rstat[gw] = r; }
  uint32_t* o = xbf + (size_t)gw * 384;
  o[2*lane]       = bfpair(v0.x, v0.y);
  o[2*lane+1]     = bfpair(v0.z, v0.w);
  o[128+2*lane]   = bfpair(v1.x, v1.y);
  o[128+2*lane+1] = bfpair(v1.z, v1.w);
  o[256+2*lane]   = bfpair(v2.x, v2.y);
  o[256+2*lane+1] = bfpair(v2.z, v2.w);
}

// -------- MFMA attention (R8 proven) --------
__global__ __launch_bounds__(256) void k_attnM(const uint32_t* __restrict__ xbf,
    const int* __restrict__ lens, const uint32_t* __restrict__ QWbf,
    const float* __restrict__ SQW, const float* __restrict__ SC,
    const float* __restrict__ mstat, const float* __restrict__ rstat,
    float* __restrict__ Pacc, float* __restrict__ Pden,
    float* __restrict__ Pc, float* __restrict__ Pmx){
  __shared__ float er_lds[64*17];
  __shared__ float tmax[4][16], tsum[4][16], tcs[4][16], fls[4][16];
  int blk = blockIdx.x;
  int ch = blk & 7, nb = blk >> 3;
  int len = lens[nb];
  int s0 = ch * ROWCH;
  if (s0 >= len) return;
  int b = nb % NB;
  int tid = threadIdx.x, wid = tid >> 6, lane = tid & 63;
  int l15 = lane & 15, mg = lane >> 4;
  int r0 = s0 + wid * 16;

  const short8* ax = (const short8*)(xbf + ((size_t)(nb*SEQLEN + r0 + l15)) * 384) + mg;
  const short8* bq = (const short8*)(QWbf + ((size_t)(b*16 + l15)) * 384) + mg;
  f32x4 acc = {0.0f, 0.0f, 0.0f, 0.0f};
  #pragma unroll
  for (int kk = 0; kk < 24; ++kk)
    acc = __builtin_amdgcn_mfma_f32_16x16x32_bf16(ax[kk*4], bq[kk*4], acc, 0, 0, 0);
  float sqw = SQW[b*16 + l15], scc = SC[b*16 + l15];
  float sco[4];
  #pragma unroll
  for (int j = 0; j < 4; ++j){
    int s = r0 + mg*4 + j;
    float mm = mstat[(size_t)nb*SEQLEN + s];
    float v = rstat[(size_t)nb*SEQLEN + s] * (acc[j] - mm * sqw) + scc;
    sco[j] = (s < len) ? v : -3.0e38f;
  }
  float tm = fmaxf(fmaxf(sco[0], sco[1]), fmaxf(sco[2], sco[3]));
  tm = fmaxf(tm, __shfl_xor(tm, 16, 64));
  tm = fmaxf(tm, __shfl_xor(tm, 32, 64));
  float es = 0, cs = 0;
  #pragma unroll
  for (int j = 0; j < 4; ++j){
    int s = r0 + mg*4 + j;
    float e = (sco[j] > -1.0e37f) ? __expf(sco[j] - tm) : 0.0f;
    float rr = rstat[(size_t)nb*SEQLEN + s];
    float er = e * rr;
    er_lds[(wid*16 + mg*4 + j)*17 + l15] = er;
    es += e;
    cs = fmaf(er, mstat[(size_t)nb*SEQLEN + s], cs);
  }
  es += __shfl_xor(es, 16, 64); es += __shfl_xor(es, 32, 64);
  cs += __shfl_xor(cs, 16, 64); cs += __shfl_xor(cs, 32, 64);
  if (lane < 16){ tmax[wid][lane] = tm; tsum[wid][lane] = es; tcs[wid][lane] = cs; }
  __syncthreads();
  if (tid < 16){
    int hh = tid;
    float M = fmaxf(fmaxf(tmax[0][hh], tmax[1][hh]), fmaxf(tmax[2][hh], tmax[3][hh]));
    float D = 0, C = 0;
    #pragma unroll
    for (int w = 0; w < 4; ++w){
      float f = (tmax[w][hh] > -1.0e37f) ? __expf(tmax[w][hh] - M) : 0.0f;
      fls[w][hh] = f;
      D = fmaf(f, tsum[w][hh], D);
      C = fmaf(f, tcs[w][hh], C);
    }
    if (hh < NHEAD){
      Pmx[(size_t)blk*NHEAD + hh] = M;
      Pden[(size_t)blk*NHEAD + hh] = D;
      Pc[(size_t)blk*NHEAD + hh] = C;
    }
  }
  __syncthreads();
  #pragma unroll
  for (int t = 0; t < 4; ++t){
    int i = tid + t*256;
    int row = i >> 4, hh = i & 15;
    er_lds[row*17 + hh] *= fls[row >> 4][hh];
  }
  __syncthreads();

  int h0 = wid * 3;
  float a[3][12];
  #pragma unroll
  for (int j = 0; j < 3; ++j)
    #pragma unroll
    for (int c = 0; c < 12; ++c) a[j][c] = 0.0f;
  const uint32_t* xr0 = xbf + ((size_t)(nb*SEQLEN + s0)) * 384 + lane*6;
  int nrows = len - s0; if (nrows > ROWCH) nrows = ROWCH;
  for (int s = 0; s < nrows; ++s){
    const uint32_t* xr = xr0 + (size_t)s * 384;
    uint2 u01 = *(const uint2*)(xr);
    uint2 u23 = *(const uint2*)(xr + 2);
    uint2 u45 = *(const uint2*)(xr + 4);
    float e0 = er_lds[s*17 + h0], e1 = er_lds[s*17 + h0 + 1], e2 = er_lds[s*17 + h0 + 2];
    float x[12];
    x[0]  = __uint_as_float(u01.x << 16); x[1]  = __uint_as_float(u01.x & 0xFFFF0000u);
    x[2]  = __uint_as_float(u01.y << 16); x[3]  = __uint_as_float(u01.y & 0xFFFF0000u);
    x[4]  = __uint_as_float(u23.x << 16); x[5]  = __uint_as_float(u23.x & 0xFFFF0000u);
    x[6]  = __uint_as_float(u23.y << 16); x[7]  = __uint_as_float(u23.y & 0xFFFF0000u);
    x[8]  = __uint_as_float(u45.x << 16); x[9]  = __uint_as_float(u45.x & 0xFFFF0000u);
    x[10] = __uint_as_float(u45.y << 16); x[11] = __uint_as_float(u45.y & 0xFFFF0000u);
    #pragma unroll
    for (int c = 0; c < 12; ++c){
      a[0][c] = fmaf(e0, x[c], a[0][c]);
      a[1][c] = fmaf(e1, x[c], a[1][c]);
      a[2][c] = fmaf(e2, x[c], a[2][c]);
    }
  }
  #pragma unroll
  for (int j = 0; j < 3; ++j){
    float* p = Pacc + ((size_t)blk*NHEAD + h0 + j) * DMODEL + lane*12;
    #pragma unroll
    for (int c = 0; c < 12; c += 4)
      *(float4*)(p + c) = make_float4(a[j][c], a[j][c+1], a[j][c+2], a[j][c+3]);
  }
}

// -------- combine --------
__global__ __launch_bounds__(256) void k_comb(const float* __restrict__ Pacc,
    const float* __restrict__ Pden, const float* __restrict__ Pc,
    const float* __restrict__ Pmx, const int* __restrict__ lens,
    const float* __restrict__ snw, const float* __restrict__ snb,
    float* __restrict__ wsum){
  int tid = blockIdx.x * 256 + threadIdx.x;
  int d = tid % DMODEL;
  int t = tid / DMODEL;
  int h = t % NHEAD;
  int b = t / NHEAD;
  float vec = 0.0f, csum = 0.0f;
  #pragma unroll
  for (int n = 0; n < NDOM; ++n){
    int nb = n*NB + b;
    int len = lens[nb];
    int na = (len + ROWCH - 1) >> 6; if (na > NCH) na = NCH;
    size_t p0 = (size_t)(nb * NCH) * NHEAD + h;
    float M = -3.0e38f;
    for (int c = 0; c < na; ++c) M = fmaxf(M, Pmx[p0 + (size_t)c*NHEAD]);
    float D = 0, V = 0, C = 0;
    for (int c = 0; c < na; ++c){
      size_t pi = p0 + (size_t)c*NHEAD;
      float w = __expf(Pmx[pi] - M);
      D = fmaf(w, Pden[pi], D);
      V = fmaf(w, Pacc[pi*DMODEL + d], V);
      C = fmaf(w, Pc[pi], C);
    }
    float inv = 1.0f / D;
    vec = fmaf(V, inv, vec);
    csum = fmaf(C, inv, csum);
  }
  wsum[tid] = (vec - csum) * snw[d] + 3.0f * snb[d];
}

// -------- ctxsum --------
__global__ __launch_bounds__(256) void k_ctxv2(const float* __restrict__ wsum,
    const float* __restrict__ Wv, const float* __restrict__ bv, float* __restrict__ ctxsum){
  int gw = (blockIdx.x * 256 + threadIdx.x) >> 6;
  int lane = threadIdx.x & 63;
  int sl = lane & 7, g = lane >> 3;
  int bg = gw & 7; int j0 = (gw >> 3) * 4;
  int h = j0 >> 6;
  const float4* a4 = (const float4*)(wsum + ((size_t)(bg*8 + g) * NHEAD + h) * DMODEL);
  const float4* w0 = (const float4*)(Wv + (size_t)(j0+0) * DMODEL);
  const float4* w1 = (const float4*)(Wv + (size_t)(j0+1) * DMODEL);
  const float4* w2 = (const float4*)(Wv + (size_t)(j0+2) * DMODEL);
  const float4* w3 = (const float4*)(Wv + (size_t)(j0+3) * DMODEL);
  float acc0 = 0, acc1 = 0, acc2 = 0, acc3 = 0;
  #pragma unroll 4
  for (int i = 0; i < DMODEL/32; ++i){
    float4 av = a4[i*8 + sl];
    acc0 += dot4f(av, w0[i*8 + sl]);
    acc1 += dot4f(av, w1[i*8 + sl]);
    acc2 += dot4f(av, w2[i*8 + sl]);
    acc3 += dot4f(av, w3[i*8 + sl]);
  }
  #pragma unroll
  for (int o = 1; o <= 4; o <<= 1){
    acc0 += __shfl_xor(acc0, o, 64);
    acc1 += __shfl_xor(acc1, o, 64);
    acc2 += __shfl_xor(acc2, o, 64);
    acc3 += __shfl_xor(acc3, o, 64);
  }
  if (sl == 0){
    float4 bb = *(const float4*)(bv + j0);
    *(float4*)(ctxsum + (size_t)(bg*8 + g) * DMODEL + j0) =
      make_float4(acc0 + 3.0f*bb.x, acc1 + 3.0f*bb.y, acc2 + 3.0f*bb.z, acc3 + 3.0f*bb.w);
  }
}

// -------- gate + residual --------
__global__ __launch_bounds__(256) void k_gate2(const float* __restrict__ ctx,
    const float* __restrict__ sctx, const float* __restrict__ Wg,
    const float* __restrict__ gb, float* __restrict__ out){
  int gw = (blockIdx.x * 256 + threadIdx.x) >> 6;
  int lane = threadIdx.x & 63;
  int sl = lane & 7, g = lane >> 3;
  int bg = gw & 7; int j0 = (gw >> 3) * 4;
  int row = bg*8 + g;
  const float4* c4 = (const float4*)(ctx + (size_t)row * DMODEL);
  const float4* s4 = (const float4*)(sctx + (size_t)row * DMODEL);
  const float4* wr0 = (const float4*)(Wg + (size_t)(j0+0) * 2 * DMODEL);
  const float4* wr1 = (const float4*)(Wg + (size_t)(j0+1) * 2 * DMODEL);
  const float4* wr2 = (const float4*)(Wg + (size_t)(j0+2) * 2 * DMODEL);
  const float4* wr3 = (const float4*)(Wg + (size_t)(j0+3) * 2 * DMODEL);
  float acc0 = 0, acc1 = 0, acc2 = 0, acc3 = 0;
  #pragma unroll 4
  for (int i = 0; i < DMODEL/32; ++i){
    float4 cv = c4[i*8 + sl], sv = s4[i*8 + sl];
    acc0 += dot4f(cv, wr0[i*8 + sl]) + dot4f(sv, wr0[192 + i*8 + sl]);
    acc1 += dot4f(cv, wr1[i*8 + sl]) + dot4f(sv, wr1[192 + i*8 + sl]);
    acc2 += dot4f(cv, wr2[i*8 + sl]) + dot4f(sv, wr2[192 + i*8 + sl]);
    acc3 += dot4f(cv, wr3[i*8 + sl]) + dot4f(sv, wr3[192 + i*8 + sl]);
  }
  #pragma unroll
  for (int o = 1; o <= 4; o <<= 1){
    acc0 += __shfl_xor(acc0, o, 64);
    acc1 += __shfl_xor(acc1, o, 64);
    acc2 += __shfl_xor(acc2, o, 64);
    acc3 += __shfl_xor(acc3, o, 64);
  }
  if (sl == 0){
    size_t o = (size_t)row * DMODEL + j0;
    float4 bb = *(const float4*)(gb + j0);
    float4 cc = *(const float4*)(ctx + o);
    float4 ss = *(const float4*)(sctx + o);
    float4 v;
    v.x = cc.x + ss.x / (1.0f + __expf(-(acc0 + bb.x)));
    v.y = cc.y + ss.y / (1.0f + __expf(-(acc1 + bb.y)));
    v.z = cc.z + ss.z / (1.0f + __expf(-(acc2 + bb.z)));
    v.w = cc.w + ss.w / (1.0f + __expf(-(acc3 + bb.w)));
    *(float4*)(out + o) = v;
  }
}

// -------- classifier final dot --------
__global__ __launch_bounds__(256) void k_cls2(const float* __restrict__ h2,
    const float* __restrict__ w2, const float* __restrict__ b2, float* __restrict__ out){
  int b = blockIdx.x; int t = threadIdx.x;
  float acc = 0;
  for (int j = t; j < FFNH; j += 256) acc = fmaf(h2[(size_t)b*FFNH + j], w2[j], acc);
  acc = wsum64(acc);
  __shared__ float sh[4];
  if ((t & 63) == 0) sh[t >> 6] = acc;
  __syncthreads();
  if (t == 0) out[b] = sh[0] + sh[1] + sh[2] + sh[3] + b2[0];
}

extern "C" void kernel_launch(void* const* d_in, const int* in_sizes, int n_in,
                              void* d_out, int out_size, void* d_ws, size_t ws_size,
                              hipStream_t stream){
  const float* in_ctx = (const float*)d_in[0];
  const float* seq    = (const float*)d_in[1];
  const int*   lens   = (const int*)d_in[2];
  const float* qn_w   = (const float*)d_in[3];
  const float* qn_b   = (const float*)d_in[4];
  const float* sn_w   = (const float*)d_in[5];
  const float* sn_b   = (const float*)d_in[6];
  const float* in_w   = (const float*)d_in[7];
  const float* in_b   = (const float*)d_in[8];
  const float* out_w  = (const float*)d_in[9];
  const float* out_b  = (const float*)d_in[10];
  const float* gate_w = (const float*)d_in[11];
  const float* gate_b = (const float*)d_in[12];
  const float* fln_w  = (const float*)d_in[13];
  const float* fln_b  = (const float*)d_in[14];
  const float* fw1    = (const float*)d_in[15];
  const float* fb1    = (const float*)d_in[16];
  const float* fw2    = (const float*)d_in[17];
  const float* fb2    = (const float*)d_in[18];
  const float* on_w   = (const float*)d_in[19];
  const float* on_b   = (const float*)d_in[20];
  const float* cl_w   = (const float*)d_in[21];
  const float* cl_b   = (const float*)d_in[22];
  const float* cw1    = (const float*)d_in[23];
  const float* cb1    = (const float*)d_in[24];
  const float* cw2    = (const float*)d_in[25];
  const float* cb2    = (const float*)d_in[26];

  float* wsf = (float*)d_ws;
  size_t off = 0;
  auto alloc = [&](size_t n){ float* p = wsf + off; off += n; return p; };
  float* c0     = alloc((size_t)NB*DMODEL);
  float* c1     = alloc((size_t)NB*DMODEL);
  float* cmid   = alloc((size_t)NB*DMODEL);
  uint32_t* QWbf = (uint32_t*)alloc((size_t)NB*16*384);
  float* SQWb   = alloc((size_t)NB*16);
  float* SCb    = alloc((size_t)NB*16);
  uint32_t* xbf = (uint32_t*)alloc((size_t)NBROWS*SEQLEN*384);
  float* mstat  = alloc((size_t)NBROWS*SEQLEN);
  float* rstat  = alloc((size_t)NBROWS*SEQLEN);
  float* Pacc   = alloc((size_t)NBROWS*NCH*NHEAD*DMODEL);
  float* Pden   = alloc((size_t)NBROWS*NCH*NHEAD);
  float* Pc     = alloc((size_t)NBROWS*NCH*NHEAD);
  float* Pmx    = alloc((size_t)NBROWS*NCH*NHEAD);
  float* wsumb  = alloc((size_t)NB*NHEAD*DMODEL);
  float* ctxsum = alloc((size_t)NB*DMODEL);
  float* sctx   = alloc((size_t)NB*DMODEL);
  float* h0     = alloc((size_t)NB*DMODEL);
  float* h1     = alloc((size_t)NB*FFNH);
  uint32_t* fw1b = (uint32_t*)alloc((size_t)NBLK*FFNH*DMODEL/2);
  uint32_t* fw2b = (uint32_t*)alloc((size_t)NBLK*DMODEL*FFNH/2);
  (void)ws_size; (void)in_sizes; (void)n_in; (void)out_size;

  const int nwdw = NBLK*FFNH*DMODEL/2;   // 2,359,296 dwords per matrix set
  hipMemcpyAsync(c0, in_ctx, (size_t)NB*DMODEL*sizeof(float), hipMemcpyDeviceToDevice, stream);
  k_w2bf<<<(nwdw + 255)/256, 256, 0, stream>>>(fw1, fw1b, nwdw);
  k_w2bf<<<(nwdw + 255)/256, 256, 0, stream>>>(fw2, fw2b, nwdw);
  k_prep<<<(NBROWS*SEQLEN)/4, 256, 0, stream>>>(seq, lens, xbf, mstat, rstat);

  float* cur = c0; float* nxt = c1;
  for (int l = 0; l < NBLK; ++l){
    const float* Wq = in_w + (size_t)l * 3 * DMODEL * DMODEL;
    const float* Wk = Wq + (size_t)DMODEL * DMODEL;
    const float* Wv = Wq + (size_t)2 * DMODEL * DMODEL;
    const float* bq = in_b + (size_t)l * 3 * DMODEL;
    const float* bk = bq + DMODEL;
    const float* bv = bq + 2 * DMODEL;

    k_qhead<<<256, 256, 0, stream>>>(cur, qn_w + l*DMODEL, qn_b + l*DMODEL,
        Wq, bq, Wk, bk, sn_w + l*DMODEL, sn_b + l*DMODEL, QWbf, SQWb, SCb);
    k_attnM<<<NBROWS*NCH, 256, 0, stream>>>(xbf, lens, QWbf, SQWb, SCb, mstat, rstat, Pacc, Pden, Pc, Pmx);
    k_comb<<<(NB*NHEAD*DMODEL)/256, 256, 0, stream>>>(Pacc, Pden, Pc, Pmx, lens, sn_w + l*DMODEL, sn_b + l*DMODEL, wsumb);
    k_ctxv2<<<384, 256, 0, stream>>>(wsumb, Wv, bv, ctxsum);
    k_gemmW<DMODEL,DMODEL,2,false><<<384, 256, 0, stream>>>(ctxsum, out_w + (size_t)l*DMODEL*DMODEL, out_b + l*DMODEL, nullptr, sctx);
    k_gate2<<<384, 256, 0, stream>>>(cur, sctx, gate_w + (size_t)l*DMODEL*2*DMODEL, gate_b + l*DMODEL, cmid);
    k_ln<<<16, 256, 0, stream>>>(cmid, fln_w + l*DMODEL, fln_b + l*DMODEL, h0, NB);
    k_gemmWbf<DMODEL,FFNH,1,false><<<1536, 256, 0, stream>>>(h0, fw1b + (size_t)l*FFNH*DMODEL/2, fb1 + l*FFNH, nullptr, h1);
    k_gemmWbf<FFNH,DMODEL,0,true><<<384, 256, 0, stream>>>(h1, fw2b + (size_t)l*DMODEL*FFNH/2, fb2 + l*DMODEL, cmid, nxt);
    float* t = cur; cur = nxt; nxt = t;
  }

  k_ln2<<<16, 256, 0, stream>>>(cur, on_w, on_b, cl_w, cl_b, h0, NB);
  k_gemmW<DMODEL,FFNH,1,false><<<1536, 256, 0, stream>>>(h0, cw1, cb1, nullptr, h1);
  k_cls2<<<64, 256, 0, stream>>>(h1, cw2, cb2, (float*)d_out);
}

// Round 13
// 550.441 us; speedup vs baseline: 1.0397x; 1.0233x over previous
//
#include <hip/hip_runtime.h>
#include <hip/hip_bf16.h>
#include <cstdint>

#define DMODEL 768
#define NB 64
#define NHEAD 12
#define DHEAD 64
#define SEQLEN 512
#define NDOM 3
#define NBLK 2
#define FFNH 3072
#define NBROWS (NDOM*NB)   // 192
#define NCH 8              // 64-row chunks
#define ROWCH 64

typedef __attribute__((ext_vector_type(8))) short short8;
typedef __attribute__((ext_vector_type(4))) float f32x4;

__device__ __forceinline__ float wsum64(float v){
  #pragma unroll
  for (int o = 32; o; o >>= 1) v += __shfl_xor(v, o, 64);
  return v;
}
__device__ __forceinline__ float dot4f(float4 a, float4 b){
  return fmaf(a.x, b.x, fmaf(a.y, b.y, fmaf(a.z, b.z, a.w * b.w)));
}
__device__ __forceinline__ uint32_t bfpair(float lo, float hi){
  uint32_t ul = __float_as_uint(lo), uh = __float_as_uint(hi);
  ul = (ul + 0x7FFFu + ((ul >> 16) & 1u)) >> 16;
  uh = (uh + 0x7FFFu + ((uh >> 16) & 1u)) & 0xFFFF0000u;
  return ul | uh;
}

// -------- LayerNorm: one wave per row --------
__global__ __launch_bounds__(256) void k_ln(const float* __restrict__ in,
    const float* __restrict__ w, const float* __restrict__ b,
    float* __restrict__ out, int rows){
  int gw = (blockIdx.x * 256 + threadIdx.x) >> 6;
  int lane = threadIdx.x & 63;
  if (gw >= rows) return;
  const float4* x4 = (const float4*)(in + (size_t)gw * DMODEL);
  float4 v0 = x4[lane], v1 = x4[64 + lane], v2 = x4[128 + lane];
  float s = v0.x+v0.y+v0.z+v0.w + v1.x+v1.y+v1.z+v1.w + v2.x+v2.y+v2.z+v2.w;
  float q = dot4f(v0,v0) + dot4f(v1,v1) + dot4f(v2,v2);
  s = wsum64(s); q = wsum64(q);
  float m = s * (1.0f / DMODEL);
  float r = rsqrtf(q * (1.0f / DMODEL) - m * m + 1e-5f);
  const float4* w4 = (const float4*)w;
  const float4* b4 = (const float4*)b;
  float4* o4 = (float4*)(out + (size_t)gw * DMODEL);
  float4 vv[3] = {v0, v1, v2};
  #pragma unroll
  for (int seg = 0; seg < 3; ++seg){
    float4 ww = w4[seg*64 + lane], bb = b4[seg*64 + lane], x = vv[seg], o;
    o.x = (x.x - m) * r * ww.x + bb.x;
    o.y = (x.y - m) * r * ww.y + bb.y;
    o.z = (x.z - m) * r * ww.z + bb.z;
    o.w = (x.w - m) * r * ww.w + bb.w;
    o4[seg*64 + lane] = o;
  }
}

// -------- double LayerNorm --------
__global__ __launch_bounds__(256) void k_ln2(const float* __restrict__ in,
    const float* __restrict__ w1, const float* __restrict__ b1,
    const float* __restrict__ w2, const float* __restrict__ b2,
    float* __restrict__ out, int rows){
  int gw = (blockIdx.x * 256 + threadIdx.x) >> 6;
  int lane = threadIdx.x & 63;
  if (gw >= rows) return;
  const float4* x4 = (const float4*)(in + (size_t)gw * DMODEL);
  float4 vv[3] = {x4[lane], x4[64 + lane], x4[128 + lane]};
  float s = 0, q = 0;
  #pragma unroll
  for (int g = 0; g < 3; ++g){ s += vv[g].x+vv[g].y+vv[g].z+vv[g].w; q += dot4f(vv[g], vv[g]); }
  s = wsum64(s); q = wsum64(q);
  float m = s * (1.0f/DMODEL);
  float r = rsqrtf(q * (1.0f/DMODEL) - m*m + 1e-5f);
  const float4* w14 = (const float4*)w1; const float4* b14 = (const float4*)b1;
  float4 yy[3]; float s2 = 0, q2 = 0;
  #pragma unroll
  for (int g = 0; g < 3; ++g){
    float4 ww = w14[g*64 + lane], bb = b14[g*64 + lane], x = vv[g], o;
    o.x = (x.x-m)*r*ww.x + bb.x; o.y = (x.y-m)*r*ww.y + bb.y;
    o.z = (x.z-m)*r*ww.z + bb.z; o.w = (x.w-m)*r*ww.w + bb.w;
    yy[g] = o; s2 += o.x+o.y+o.z+o.w; q2 += dot4f(o,o);
  }
  s2 = wsum64(s2); q2 = wsum64(q2);
  float m2 = s2 * (1.0f/DMODEL);
  float r2 = rsqrtf(q2 * (1.0f/DMODEL) - m2*m2 + 1e-5f);
  const float4* w24 = (const float4*)w2; const float4* b24 = (const float4*)b2;
  float4* o4 = (float4*)(out + (size_t)gw * DMODEL);
  #pragma unroll
  for (int g = 0; g < 3; ++g){
    float4 ww = w24[g*64 + lane], bb = b24[g*64 + lane], y = yy[g], o;
    o.x = (y.x-m2)*r2*ww.x + bb.x; o.y = (y.y-m2)*r2*ww.y + bb.y;
    o.z = (y.z-m2)*r2*ww.z + bb.z; o.w = (y.w-m2)*r2*ww.w + bb.w;
    o4[g*64 + lane] = o;
  }
}

// -------- wave-per-4-columns GEMM --------
template<int K, int NC, int ACT, bool RES>
__global__ __launch_bounds__(256) void k_gemmW(const float* __restrict__ A,
    const float* __restrict__ W, const float* __restrict__ bias,
    const float* __restrict__ res, float* __restrict__ out){
  int gw = (blockIdx.x * 256 + threadIdx.x) >> 6;
  int lane = threadIdx.x & 63;
  int sl = lane & 7, g = lane >> 3;
  int bg = gw & 7; int j0 = (gw >> 3) * 4;
  const float4* a4 = (const float4*)(A + (size_t)(bg*8 + g) * K);
  const float4* w0 = (const float4*)(W + (size_t)(j0+0) * K);
  const float4* w1 = (const float4*)(W + (size_t)(j0+1) * K);
  const float4* w2 = (const float4*)(W + (size_t)(j0+2) * K);
  const float4* w3 = (const float4*)(W + (size_t)(j0+3) * K);
  float acc0 = 0, acc1 = 0, acc2 = 0, acc3 = 0;
  #pragma unroll 4
  for (int i = 0; i < K/32; ++i){
    float4 av = a4[i*8 + sl];
    acc0 += dot4f(av, w0[i*8 + sl]);
    acc1 += dot4f(av, w1[i*8 + sl]);
    acc2 += dot4f(av, w2[i*8 + sl]);
    acc3 += dot4f(av, w3[i*8 + sl]);
  }
  #pragma unroll
  for (int o = 1; o <= 4; o <<= 1){
    acc0 += __shfl_xor(acc0, o, 64);
    acc1 += __shfl_xor(acc1, o, 64);
    acc2 += __shfl_xor(acc2, o, 64);
    acc3 += __shfl_xor(acc3, o, 64);
  }
  if (sl == 0){
    int row = bg*8 + g;
    float4 bj = *(const float4*)(bias + j0);
    float a[4] = {acc0, acc1, acc2, acc3};
    float bb[4] = {bj.x, bj.y, bj.z, bj.w};
    float v[4];
    #pragma unroll
    for (int u = 0; u < 4; ++u){
      float t = (ACT == 2) ? a[u] * (1.0f/3.0f) + bb[u] : a[u] + bb[u];
      if (ACT == 1) t = t / (1.0f + __expf(-t));
      v[u] = t;
    }
    size_t o = (size_t)row * NC + j0;
    if (RES){
      float4 rr = *(const float4*)(res + o);
      v[0] += rr.x; v[1] += rr.y; v[2] += rr.z; v[3] += rr.w;
    }
    *(float4*)(out + o) = make_float4(v[0], v[1], v[2], v[3]);
  }
}

// -------- fused query head: LN(ctx) + Wq proj + qproj/reductions --------
// block = (b, head-quarter qq); qq==3 writes the 4 pad heads (zeros).
__global__ __launch_bounds__(256) void k_qhead(const float* __restrict__ cur,
    const float* __restrict__ qn_w, const float* __restrict__ qn_b,
    const float* __restrict__ Wq, const float* __restrict__ bq,
    const float* __restrict__ Wk, const float* __restrict__ bk,
    const float* __restrict__ snw, const float* __restrict__ snb,
    uint32_t* __restrict__ QWbf, float* __restrict__ SQW, float* __restrict__ SC){
  __shared__ float qln_lds[DMODEL];
  __shared__ float qh_lds[256];
  __shared__ float red[8];
  int blk = blockIdx.x;
  int qq = blk & 3, b = blk >> 2;
  int tid = threadIdx.x, lane = tid & 63, wid = tid >> 6;
  if (qq == 3){
    int w16 = b*16 + 12 + wid;
    uint32_t* qwout = QWbf + (size_t)w16 * 384;
    #pragma unroll
    for (int k = 0; k < 6; ++k) qwout[k*64 + lane] = 0;
    if (lane == 0){ SQW[w16] = 0.0f; SC[w16] = 0.0f; }
    return;
  }
  // stage 1: LN row b
  {
    float x0 = cur[(size_t)b*DMODEL + tid];
    float x1 = cur[(size_t)b*DMODEL + 256 + tid];
    float x2 = cur[(size_t)b*DMODEL + 512 + tid];
    float s = x0 + x1 + x2;
    float q = x0*x0 + x1*x1 + x2*x2;
    s = wsum64(s); q = wsum64(q);
    if (lane == 0){ red[wid] = s; red[4 + wid] = q; }
    __syncthreads();
    float st = red[0] + red[1] + red[2] + red[3];
    float qt = red[4] + red[5] + red[6] + red[7];
    float m = st * (1.0f/DMODEL);
    float r = rsqrtf(qt * (1.0f/DMODEL) - m*m + 1e-5f);
    qln_lds[tid]       = (x0 - m)*r*qn_w[tid]       + qn_b[tid];
    qln_lds[256 + tid] = (x1 - m)*r*qn_w[256 + tid] + qn_b[256 + tid];
    qln_lds[512 + tid] = (x2 - m)*r*qn_w[512 + tid] + qn_b[512 + tid];
  }
  __syncthreads();
  // stage 2: qh col = qq*256 + tid
  {
    int col = qq*256 + tid;
    const float4* wr = (const float4*)(Wq + (size_t)col * DMODEL);
    const float4* ql = (const float4*)qln_lds;
    float acc = 0;
    #pragma unroll 8
    for (int i = 0; i < 192; ++i) acc += dot4f(ql[i], wr[i]);
    qh_lds[tid] = acc + bq[col];
  }
  __syncthreads();
  // stage 3: qpr for head hh = qq*4 + wid
  {
    int hh = qq*4 + wid;
    int w16 = b*16 + hh;
    const float* qrow = qh_lds + wid*64;
    const float* wbase = Wk + (size_t)hh * DHEAD * DMODEL;
    float qa[6] = {0,0,0,0,0,0}, qb[6] = {0,0,0,0,0,0};
    for (int e = 0; e < DHEAD; ++e){
      float qv = qrow[e];
      const float* wr = wbase + (size_t)e * DMODEL + 2*lane;
      #pragma unroll
      for (int k = 0; k < 6; ++k){
        qa[k] = fmaf(qv, wr[k*128], qa[k]);
        qb[k] = fmaf(qv, wr[k*128 + 1], qb[k]);
      }
    }
    uint32_t* qwout = QWbf + (size_t)w16 * 384;
    float s1 = 0, s2 = 0;
    #pragma unroll
    for (int k = 0; k < 6; ++k){
      int d0 = k*128 + 2*lane;
      float va = qa[k] * snw[d0]   * 0.125f;
      float vb = qb[k] * snw[d0+1] * 0.125f;
      uint32_t pr = bfpair(va, vb);
      qwout[k*64 + lane] = pr;
      s1 += __uint_as_float(pr << 16) + __uint_as_float(pr & 0xFFFF0000u);
      s2 = fmaf(qa[k], snb[d0], fmaf(qb[k], snb[d0+1], s2));
    }
    float s3 = qrow[lane] * bk[hh*DHEAD + lane];
    s1 = wsum64(s1); s2 = wsum64(s2); s3 = wsum64(s3);
    if (lane == 0){ SQW[w16] = s1; SC[w16] = 0.125f * (s2 + s3); }
  }
}

// -------- prep (once): LN stats + bf16 copy, len-gated --------
__global__ __launch_bounds__(256) void k_prep(const float* __restrict__ seq,
    const int* __restrict__ lens, uint32_t* __restrict__ xbf,
    float* __restrict__ mstat, float* __restrict__ rstat){
  int gw = (blockIdx.x * 256 + threadIdx.x) >> 6;
  int lane = threadIdx.x & 63;
  int nb = gw >> 9, s = gw & 511;
  if (s >= lens[nb]) return;
  const float4* x4 = (const float4*)(seq + (size_t)gw * DMODEL);
  float4 v0 = x4[lane], v1 = x4[64 + lane], v2 = x4[128 + lane];
  float sm = v0.x+v0.y+v0.z+v0.w + v1.x+v1.y+v1.z+v1.w + v2.x+v2.y+v2.z+v2.w;
  float q = dot4f(v0,v0) + dot4f(v1,v1) + dot4f(v2,v2);
  sm = wsum64(sm); q = wsum64(q);
  float m = sm * (1.0f/DMODEL);
  float r = rsqrtf(q * (1.0f/DMODEL) - m*m + 1e-5f);
  if (lane == 0){ mstat[gw] = m; rstat[gw] = r; }
  uint32_t* o = xbf + (size_t)gw * 384;
  o[2*lane]       = bfpair(v0.x, v0.y);
  o[2*lane+1]     = bfpair(v0.z, v0.w);
  o[128+2*lane]   = bfpair(v1.x, v1.y);
  o[128+2*lane+1] = bfpair(v1.z, v1.w);
  o[256+2*lane]   = bfpair(v2.x, v2.y);
  o[256+2*lane+1] = bfpair(v2.z, v2.w);
}

// -------- MFMA attention --------
__global__ __launch_bounds__(256) void k_attnM(const uint32_t* __restrict__ xbf,
    const int* __restrict__ lens, const uint32_t* __restrict__ QWbf,
    const float* __restrict__ SQW, const float* __restrict__ SC,
    const float* __restrict__ mstat, const float* __restrict__ rstat,
    float* __restrict__ Pacc, float* __restrict__ Pden,
    float* __restrict__ Pc, float* __restrict__ Pmx){
  __shared__ float er_lds[64*17];
  __shared__ float tmax[4][16], tsum[4][16], tcs[4][16], fls[4][16];
  int blk = blockIdx.x;
  int ch = blk & 7, nb = blk >> 3;
  int len = lens[nb];
  int s0 = ch * ROWCH;
  if (s0 >= len) return;
  int b = nb % NB;
  int tid = threadIdx.x, wid = tid >> 6, lane = tid & 63;
  int l15 = lane & 15, mg = lane >> 4;
  int r0 = s0 + wid * 16;

  const short8* ax = (const short8*)(xbf + ((size_t)(nb*SEQLEN + r0 + l15)) * 384) + mg;
  const short8* bq = (const short8*)(QWbf + ((size_t)(b*16 + l15)) * 384) + mg;
  f32x4 acc = {0.0f, 0.0f, 0.0f, 0.0f};
  #pragma unroll
  for (int kk = 0; kk < 24; ++kk)
    acc = __builtin_amdgcn_mfma_f32_16x16x32_bf16(ax[kk*4], bq[kk*4], acc, 0, 0, 0);
  float sqw = SQW[b*16 + l15], scc = SC[b*16 + l15];
  float sco[4];
  #pragma unroll
  for (int j = 0; j < 4; ++j){
    int s = r0 + mg*4 + j;
    float mm = mstat[(size_t)nb*SEQLEN + s];
    float v = rstat[(size_t)nb*SEQLEN + s] * (acc[j] - mm * sqw) + scc;
    sco[j] = (s < len) ? v : -3.0e38f;
  }
  float tm = fmaxf(fmaxf(sco[0], sco[1]), fmaxf(sco[2], sco[3]));
  tm = fmaxf(tm, __shfl_xor(tm, 16, 64));
  tm = fmaxf(tm, __shfl_xor(tm, 32, 64));
  float es = 0, cs = 0;
  #pragma unroll
  for (int j = 0; j < 4; ++j){
    int s = r0 + mg*4 + j;
    float e = (sco[j] > -1.0e37f) ? __expf(sco[j] - tm) : 0.0f;
    float rr = rstat[(size_t)nb*SEQLEN + s];
    float er = e * rr;
    er_lds[(wid*16 + mg*4 + j)*17 + l15] = er;
    es += e;
    cs = fmaf(er, mstat[(size_t)nb*SEQLEN + s], cs);
  }
  es += __shfl_xor(es, 16, 64); es += __shfl_xor(es, 32, 64);
  cs += __shfl_xor(cs, 16, 64); cs += __shfl_xor(cs, 32, 64);
  if (lane < 16){ tmax[wid][lane] = tm; tsum[wid][lane] = es; tcs[wid][lane] = cs; }
  __syncthreads();
  if (tid < 16){
    int hh = tid;
    float M = fmaxf(fmaxf(tmax[0][hh], tmax[1][hh]), fmaxf(tmax[2][hh], tmax[3][hh]));
    float D = 0, C = 0;
    #pragma unroll
    for (int w = 0; w < 4; ++w){
      float f = (tmax[w][hh] > -1.0e37f) ? __expf(tmax[w][hh] - M) : 0.0f;
      fls[w][hh] = f;
      D = fmaf(f, tsum[w][hh], D);
      C = fmaf(f, tcs[w][hh], C);
    }
    if (hh < NHEAD){
      Pmx[(size_t)blk*NHEAD + hh] = M;
      Pden[(size_t)blk*NHEAD + hh] = D;
      Pc[(size_t)blk*NHEAD + hh] = C;
    }
  }
  __syncthreads();
  #pragma unroll
  for (int t = 0; t < 4; ++t){
    int i = tid + t*256;
    int row = i >> 4, hh = i & 15;
    er_lds[row*17 + hh] *= fls[row >> 4][hh];
  }
  __syncthreads();

  int h0 = wid * 3;
  float a[3][12];
  #pragma unroll
  for (int j = 0; j < 3; ++j)
    #pragma unroll
    for (int c = 0; c < 12; ++c) a[j][c] = 0.0f;
  const uint32_t* xr0 = xbf + ((size_t)(nb*SEQLEN + s0)) * 384 + lane*6;
  int nrows = len - s0; if (nrows > ROWCH) nrows = ROWCH;
  for (int s = 0; s < nrows; ++s){
    const uint32_t* xr = xr0 + (size_t)s * 384;
    uint2 u01 = *(const uint2*)(xr);
    uint2 u23 = *(const uint2*)(xr + 2);
    uint2 u45 = *(const uint2*)(xr + 4);
    float e0 = er_lds[s*17 + h0], e1 = er_lds[s*17 + h0 + 1], e2 = er_lds[s*17 + h0 + 2];
    float x[12];
    x[0]  = __uint_as_float(u01.x << 16); x[1]  = __uint_as_float(u01.x & 0xFFFF0000u);
    x[2]  = __uint_as_float(u01.y << 16); x[3]  = __uint_as_float(u01.y & 0xFFFF0000u);
    x[4]  = __uint_as_float(u23.x << 16); x[5]  = __uint_as_float(u23.x & 0xFFFF0000u);
    x[6]  = __uint_as_float(u23.y << 16); x[7]  = __uint_as_float(u23.y & 0xFFFF0000u);
    x[8]  = __uint_as_float(u45.x << 16); x[9]  = __uint_as_float(u45.x & 0xFFFF0000u);
    x[10] = __uint_as_float(u45.y << 16); x[11] = __uint_as_float(u45.y & 0xFFFF0000u);
    #pragma unroll
    for (int c = 0; c < 12; ++c){
      a[0][c] = fmaf(e0, x[c], a[0][c]);
      a[1][c] = fmaf(e1, x[c], a[1][c]);
      a[2][c] = fmaf(e2, x[c], a[2][c]);
    }
  }
  #pragma unroll
  for (int j = 0; j < 3; ++j){
    float* p = Pacc + ((size_t)blk*NHEAD + h0 + j) * DMODEL + lane*12;
    #pragma unroll
    for (int c = 0; c < 12; c += 4)
      *(float4*)(p + c) = make_float4(a[j][c], a[j][c+1], a[j][c+2], a[j][c+3]);
  }
}

// -------- combine --------
__global__ __launch_bounds__(256) void k_comb(const float* __restrict__ Pacc,
    const float* __restrict__ Pden, const float* __restrict__ Pc,
    const float* __restrict__ Pmx, const int* __restrict__ lens,
    const float* __restrict__ snw, const float* __restrict__ snb,
    float* __restrict__ wsum){
  int tid = blockIdx.x * 256 + threadIdx.x;
  int d = tid % DMODEL;
  int t = tid / DMODEL;
  int h = t % NHEAD;
  int b = t / NHEAD;
  float vec = 0.0f, csum = 0.0f;
  #pragma unroll
  for (int n = 0; n < NDOM; ++n){
    int nb = n*NB + b;
    int len = lens[nb];
    int na = (len + ROWCH - 1) >> 6; if (na > NCH) na = NCH;
    size_t p0 = (size_t)(nb * NCH) * NHEAD + h;
    float M = -3.0e38f;
    for (int c = 0; c < na; ++c) M = fmaxf(M, Pmx[p0 + (size_t)c*NHEAD]);
    float D = 0, V = 0, C = 0;
    for (int c = 0; c < na; ++c){
      size_t pi = p0 + (size_t)c*NHEAD;
      float w = __expf(Pmx[pi] - M);
      D = fmaf(w, Pden[pi], D);
      V = fmaf(w, Pacc[pi*DMODEL + d], V);
      C = fmaf(w, Pc[pi], C);
    }
    float inv = 1.0f / D;
    vec = fmaf(V, inv, vec);
    csum = fmaf(C, inv, csum);
  }
  wsum[tid] = (vec - csum) * snw[d] + 3.0f * snb[d];
}

// -------- ctxsum --------
__global__ __launch_bounds__(256) void k_ctxv2(const float* __restrict__ wsum,
    const float* __restrict__ Wv, const float* __restrict__ bv, float* __restrict__ ctxsum){
  int gw = (blockIdx.x * 256 + threadIdx.x) >> 6;
  int lane = threadIdx.x & 63;
  int sl = lane & 7, g = lane >> 3;
  int bg = gw & 7; int j0 = (gw >> 3) * 4;
  int h = j0 >> 6;
  const float4* a4 = (const float4*)(wsum + ((size_t)(bg*8 + g) * NHEAD + h) * DMODEL);
  const float4* w0 = (const float4*)(Wv + (size_t)(j0+0) * DMODEL);
  const float4* w1 = (const float4*)(Wv + (size_t)(j0+1) * DMODEL);
  const float4* w2 = (const float4*)(Wv + (size_t)(j0+2) * DMODEL);
  const float4* w3 = (const float4*)(Wv + (size_t)(j0+3) * DMODEL);
  float acc0 = 0, acc1 = 0, acc2 = 0, acc3 = 0;
  #pragma unroll 4
  for (int i = 0; i < DMODEL/32; ++i){
    float4 av = a4[i*8 + sl];
    acc0 += dot4f(av, w0[i*8 + sl]);
    acc1 += dot4f(av, w1[i*8 + sl]);
    acc2 += dot4f(av, w2[i*8 + sl]);
    acc3 += dot4f(av, w3[i*8 + sl]);
  }
  #pragma unroll
  for (int o = 1; o <= 4; o <<= 1){
    acc0 += __shfl_xor(acc0, o, 64);
    acc1 += __shfl_xor(acc1, o, 64);
    acc2 += __shfl_xor(acc2, o, 64);
    acc3 += __shfl_xor(acc3, o, 64);
  }
  if (sl == 0){
    float4 bb = *(const float4*)(bv + j0);
    *(float4*)(ctxsum + (size_t)(bg*8 + g) * DMODEL + j0) =
      make_float4(acc0 + 3.0f*bb.x, acc1 + 3.0f*bb.y, acc2 + 3.0f*bb.z, acc3 + 3.0f*bb.w);
  }
}

// -------- gate + residual --------
__global__ __launch_bounds__(256) void k_gate2(const float* __restrict__ ctx,
    const float* __restrict__ sctx, const float* __restrict__ Wg,
    const float* __restrict__ gb, float* __restrict__ out){
  int gw = (blockIdx.x * 256 + threadIdx.x) >> 6;
  int lane = threadIdx.x & 63;
  int sl = lane & 7, g = lane >> 3;
  int bg = gw & 7; int j0 = (gw >> 3) * 4;
  int row = bg*8 + g;
  const float4* c4 = (const float4*)(ctx + (size_t)row * DMODEL);
  const float4* s4 = (const float4*)(sctx + (size_t)row * DMODEL);
  const float4* wr0 = (const float4*)(Wg + (size_t)(j0+0) * 2 * DMODEL);
  const float4* wr1 = (const float4*)(Wg + (size_t)(j0+1) * 2 * DMODEL);
  const float4* wr2 = (const float4*)(Wg + (size_t)(j0+2) * 2 * DMODEL);
  const float4* wr3 = (const float4*)(Wg + (size_t)(j0+3) * 2 * DMODEL);
  float acc0 = 0, acc1 = 0, acc2 = 0, acc3 = 0;
  #pragma unroll 4
  for (int i = 0; i < DMODEL/32; ++i){
    float4 cv = c4[i*8 + sl], sv = s4[i*8 + sl];
    acc0 += dot4f(cv, wr0[i*8 + sl]) + dot4f(sv, wr0[192 + i*8 + sl]);
    acc1 += dot4f(cv, wr1[i*8 + sl]) + dot4f(sv, wr1[192 + i*8 + sl]);
    acc2 += dot4f(cv, wr2[i*8 + sl]) + dot4f(sv, wr2[192 + i*8 + sl]);
    acc3 += dot4f(cv, wr3[i*8 + sl]) + dot4f(sv, wr3[192 + i*8 + sl]);
  }
  #pragma unroll
  for (int o = 1; o <= 4; o <<= 1){
    acc0 += __shfl_xor(acc0, o, 64);
    acc1 += __shfl_xor(acc1, o, 64);
    acc2 += __shfl_xor(acc2, o, 64);
    acc3 += __shfl_xor(acc3, o, 64);
  }
  if (sl == 0){
    size_t o = (size_t)row * DMODEL + j0;
    float4 bb = *(const float4*)(gb + j0);
    float4 cc = *(const float4*)(ctx + o);
    float4 ss = *(const float4*)(sctx + o);
    float4 v;
    v.x = cc.x + ss.x / (1.0f + __expf(-(acc0 + bb.x)));
    v.y = cc.y + ss.y / (1.0f + __expf(-(acc1 + bb.y)));
    v.z = cc.z + ss.z / (1.0f + __expf(-(acc2 + bb.z)));
    v.w = cc.w + ss.w / (1.0f + __expf(-(acc3 + bb.w)));
    *(float4*)(out + o) = v;
  }
}

// -------- classifier final dot --------
__global__ __launch_bounds__(256) void k_cls2(const float* __restrict__ h2,
    const float* __restrict__ w2, const float* __restrict__ b2, float* __restrict__ out){
  int b = blockIdx.x; int t = threadIdx.x;
  float acc = 0;
  for (int j = t; j < FFNH; j += 256) acc = fmaf(h2[(size_t)b*FFNH + j], w2[j], acc);
  acc = wsum64(acc);
  __shared__ float sh[4];
  if ((t & 63) == 0) sh[t >> 6] = acc;
  __syncthreads();
  if (t == 0) out[b] = sh[0] + sh[1] + sh[2] + sh[3] + b2[0];
}

extern "C" void kernel_launch(void* const* d_in, const int* in_sizes, int n_in,
                              void* d_out, int out_size, void* d_ws, size_t ws_size,
                              hipStream_t stream){
  const float* in_ctx = (const float*)d_in[0];
  const float* seq    = (const float*)d_in[1];
  const int*   lens   = (const int*)d_in[2];
  const float* qn_w   = (const float*)d_in[3];
  const float* qn_b   = (const float*)d_in[4];
  const float* sn_w   = (const float*)d_in[5];
  const float* sn_b   = (const float*)d_in[6];
  const float* in_w   = (const float*)d_in[7];
  const float* in_b   = (const float*)d_in[8];
  const float* out_w  = (const float*)d_in[9];
  const float* out_b  = (const float*)d_in[10];
  const float* gate_w = (const float*)d_in[11];
  const float* gate_b = (const float*)d_in[12];
  const float* fln_w  = (const float*)d_in[13];
  const float* fln_b  = (const float*)d_in[14];
  const float* fw1    = (const float*)d_in[15];
  const float* fb1    = (const float*)d_in[16];
  const float* fw2    = (const float*)d_in[17];
  const float* fb2    = (const float*)d_in[18];
  const float* on_w   = (const float*)d_in[19];
  const float* on_b   = (const float*)d_in[20];
  const float* cl_w   = (const float*)d_in[21];
  const float* cl_b   = (const float*)d_in[22];
  const float* cw1    = (const float*)d_in[23];
  const float* cb1    = (const float*)d_in[24];
  const float* cw2    = (const float*)d_in[25];
  const float* cb2    = (const float*)d_in[26];

  float* wsf = (float*)d_ws;
  size_t off = 0;
  auto alloc = [&](size_t n){ float* p = wsf + off; off += n; return p; };
  float* c0     = alloc((size_t)NB*DMODEL);
  float* c1     = alloc((size_t)NB*DMODEL);
  float* cmid   = alloc((size_t)NB*DMODEL);
  uint32_t* QWbf = (uint32_t*)alloc((size_t)NB*16*384);
  float* SQWb   = alloc((size_t)NB*16);
  float* SCb    = alloc((size_t)NB*16);
  uint32_t* xbf = (uint32_t*)alloc((size_t)NBROWS*SEQLEN*384);
  float* mstat  = alloc((size_t)NBROWS*SEQLEN);
  float* rstat  = alloc((size_t)NBROWS*SEQLEN);
  float* Pacc   = alloc((size_t)NBROWS*NCH*NHEAD*DMODEL);
  float* Pden   = alloc((size_t)NBROWS*NCH*NHEAD);
  float* Pc     = alloc((size_t)NBROWS*NCH*NHEAD);
  float* Pmx    = alloc((size_t)NBROWS*NCH*NHEAD);
  float* wsumb  = alloc((size_t)NB*NHEAD*DMODEL);
  float* ctxsum = alloc((size_t)NB*DMODEL);
  float* sctx   = alloc((size_t)NB*DMODEL);
  float* h0     = alloc((size_t)NB*DMODEL);
  float* h1     = alloc((size_t)NB*FFNH);
  (void)ws_size; (void)in_sizes; (void)n_in; (void)out_size;

  hipMemcpyAsync(c0, in_ctx, (size_t)NB*DMODEL*sizeof(float), hipMemcpyDeviceToDevice, stream);
  k_prep<<<(NBROWS*SEQLEN)/4, 256, 0, stream>>>(seq, lens, xbf, mstat, rstat);

  float* cur = c0; float* nxt = c1;
  for (int l = 0; l < NBLK; ++l){
    const float* Wq = in_w + (size_t)l * 3 * DMODEL * DMODEL;
    const float* Wk = Wq + (size_t)DMODEL * DMODEL;
    const float* Wv = Wq + (size_t)2 * DMODEL * DMODEL;
    const float* bq = in_b + (size_t)l * 3 * DMODEL;
    const float* bk = bq + DMODEL;
    const float* bv = bq + 2 * DMODEL;

    k_qhead<<<256, 256, 0, stream>>>(cur, qn_w + l*DMODEL, qn_b + l*DMODEL,
        Wq, bq, Wk, bk, sn_w + l*DMODEL, sn_b + l*DMODEL, QWbf, SQWb, SCb);
    k_attnM<<<NBROWS*NCH, 256, 0, stream>>>(xbf, lens, QWbf, SQWb, SCb, mstat, rstat, Pacc, Pden, Pc, Pmx);
    k_comb<<<(NB*NHEAD*DMODEL)/256, 256, 0, stream>>>(Pacc, Pden, Pc, Pmx, lens, sn_w + l*DMODEL, sn_b + l*DMODEL, wsumb);
    k_ctxv2<<<384, 256, 0, stream>>>(wsumb, Wv, bv, ctxsum);
    k_gemmW<DMODEL,DMODEL,2,false><<<384, 256, 0, stream>>>(ctxsum, out_w + (size_t)l*DMODEL*DMODEL, out_b + l*DMODEL, nullptr, sctx);
    k_gate2<<<384, 256, 0, stream>>>(cur, sctx, gate_w + (size_t)l*DMODEL*2*DMODEL, gate_b + l*DMODEL, cmid);
    k_ln<<<16, 256, 0, stream>>>(cmid, fln_w + l*DMODEL, fln_b + l*DMODEL, h0, NB);
    k_gemmW<DMODEL,FFNH,1,false><<<1536, 256, 0, stream>>>(h0, fw1 + (size_t)l*FFNH*DMODEL, fb1 + l*FFNH, nullptr, h1);
    k_gemmW<FFNH,DMODEL,0,true><<<384, 256, 0, stream>>>(h1, fw2 + (size_t)l*DMODEL*FFNH, fb2 + l*DMODEL, cmid, nxt);
    float* t = cur; cur = nxt; nxt = t;
  }

  k_ln2<<<16, 256, 0, stream>>>(cur, on_w, on_b, cl_w, cl_b, h0, NB);
  k_gemmW<DMODEL,FFNH,1,false><<<1536, 256, 0, stream>>>(h0, cw1, cb1, nullptr, h1);
  k_cls2<<<64, 256, 0, stream>>>(h1, cw2, cb2, (float*)d_out);
}